// Round 5
// baseline (553.446 us; speedup 1.0000x reference)
//
#include <hip/hip_runtime.h>
#include <hip/hip_fp16.h>

#define TPB 256
#define SCAN_B 256
#define NB2 4096         // CSR-fill buckets
#define BPAD 16          // bucket cursor padding (ints) -> one 64B line each

typedef __attribute__((ext_vector_type(8))) short bf16x8;
typedef __attribute__((ext_vector_type(4))) float f32x4;

// ---------- fp32 -> bf16 hi/lo split ----------
__device__ inline void split1(float x, unsigned short& h, unsigned short& l) {
  unsigned xb = __float_as_uint(x);
  h = (unsigned short)(xb >> 16);
  float hf = __uint_as_float(xb & 0xFFFF0000u);
  float lf = x - hf;
  l = (unsigned short)(__float_as_uint(lf) >> 16);
}

__device__ inline void split4(const float4 v, ushort4& h, ushort4& l) {
  split1(v.x, h.x, l.x);
  split1(v.y, h.y, l.y);
  split1(v.z, h.z, l.z);
  split1(v.w, h.w, l.w);
}

// ---------- degree / rowptr ----------

__global__ void k_hist(const int* __restrict__ dst, int* __restrict__ cnt, int E) {
  int e = blockIdx.x * blockDim.x + threadIdx.x;
  if (e < E) atomicAdd(cnt + dst[e], 1);
}

__global__ void k_dinv_from_cnt(const int* __restrict__ cnt, float* __restrict__ dinv, int N) {
  int i = blockIdx.x * blockDim.x + threadIdx.x;
  if (i < N) dinv[i] = rsqrtf((float)(cnt[i] + 1));
}

__global__ void k_scanA(const int* __restrict__ cnt, int* __restrict__ rowptr1,
                        int* __restrict__ bsum, int N) {
  __shared__ int s[SCAN_B];
  int i = blockIdx.x * SCAN_B + threadIdx.x;
  int v = (i < N) ? cnt[i] : 0;
  s[threadIdx.x] = v;
  __syncthreads();
  for (int off = 1; off < SCAN_B; off <<= 1) {
    int t = (threadIdx.x >= (unsigned)off) ? s[threadIdx.x - off] : 0;
    __syncthreads();
    s[threadIdx.x] += t;
    __syncthreads();
  }
  if (i < N) rowptr1[i] = s[threadIdx.x];
  if (threadIdx.x == SCAN_B - 1) bsum[blockIdx.x] = s[SCAN_B - 1];
}

__global__ void k_scanB(int* __restrict__ bsum, int nb) {
  __shared__ int s[1024];
  int v = (threadIdx.x < (unsigned)nb) ? bsum[threadIdx.x] : 0;
  s[threadIdx.x] = v;
  __syncthreads();
  for (int off = 1; off < 1024; off <<= 1) {
    int t = (threadIdx.x >= (unsigned)off) ? s[threadIdx.x - off] : 0;
    __syncthreads();
    s[threadIdx.x] += t;
    __syncthreads();
  }
  if (threadIdx.x < (unsigned)nb) bsum[threadIdx.x] = s[threadIdx.x] - v;
}

__global__ void k_scanC(int* __restrict__ rowptr, const int* __restrict__ bsum, int N) {
  int i = blockIdx.x * SCAN_B + threadIdx.x;
  if (i < N) rowptr[i + 1] += bsum[blockIdx.x];
  if (i == 0) rowptr[0] = 0;
}

__global__ void k_copy_i32(int* __restrict__ d, const int* __restrict__ s, int n) {
  int i = blockIdx.x * blockDim.x + threadIdx.x;
  if (i < n) d[i] = s[i];
}

// ---------- bucketed CSR fill v2 ----------
// bucket b = contiguous node range [b*bpn,(b+1)*bpn) -> its bdata region is
// [rowptr[b*bpn], rowptr[min((b+1)*bpn,N)]) -- offsets derived from rowptr, no
// counting pass. Edge packed as src | local<<20 (requires N < 2^20, bpn<=256).

__global__ void k_bpos_init(const int* __restrict__ rowptr, int* __restrict__ bpos,
                            int N, int bpn) {
  int b = blockIdx.x * blockDim.x + threadIdx.x;
  if (b < NB2) bpos[b * BPAD] = rowptr[min(b * bpn, N)];
}

__global__ void k_bfill2(const int* __restrict__ src, const int* __restrict__ dst,
                         int* __restrict__ bpos, unsigned* __restrict__ bdata,
                         int E, int bpn) {
  int stride = gridDim.x * blockDim.x;
  for (int e = blockIdx.x * blockDim.x + threadIdx.x; e < E; e += stride) {
    int d = dst[e];
    int b = d / bpn;
    int p = atomicAdd(bpos + b * BPAD, 1);
    bdata[p] = (unsigned)src[e] | ((unsigned)(d - b * bpn) << 20);
  }
}

__global__ void k_bcsr2(const unsigned* __restrict__ bdata, const int* __restrict__ rowptr,
                        int* __restrict__ col, int N, int bpn) {
  __shared__ int lcnt[256];
  __shared__ int rp[257];
  const int b = blockIdx.x;
  const int nodeBase = b * bpn;
  if (nodeBase >= N) return;
  const int nn = min(bpn, N - nodeBase);
  for (int i = threadIdx.x; i < nn; i += blockDim.x) lcnt[i] = 0;
  for (int i = threadIdx.x; i <= nn; i += blockDim.x) rp[i] = rowptr[nodeBase + i];
  __syncthreads();
  const int beg = rp[0], end = rp[nn];
  for (int i = beg + threadIdx.x; i < end; i += blockDim.x) {
    unsigned w = bdata[i];
    int local = (int)(w >> 20);
    int s = atomicAdd(&lcnt[local], 1);
    col[rp[local] + s] = (int)(w & 0xFFFFFu);
  }
}

// plain fillcsr (middle-fallback only)
__global__ void k_fillcsr(const int* __restrict__ src, const int* __restrict__ dst,
                          int* __restrict__ wpos, int* __restrict__ col, int E) {
  int e = blockIdx.x * blockDim.x + threadIdx.x;
  if (e >= E) return;
  int p = atomicAdd(wpos + dst[e], 1);
  col[p] = src[e];
}

// ---------- W prep ----------
__global__ void k_prep_wt(const float* __restrict__ W, unsigned short* __restrict__ Wh,
                          unsigned short* __restrict__ Wl, int K, int C) {
  int i = blockIdx.x * blockDim.x + threadIdx.x;
  if (i >= K * C) return;
  int k = i / C, c = i % C;
  unsigned short h, l;
  split1(W[i], h, l);
  Wh[(size_t)c * K + k] = h;
  Wl[(size_t)c * K + k] = l;
}

// ---------- MFMA GEMM: Y = (X @ W) * dinv[row]; optional fp16 shadow copy ----------
template<int COUT>
__launch_bounds__(512)
__global__ void k_gemm_mfma(const float* __restrict__ X, const unsigned short* __restrict__ Wh,
                            const unsigned short* __restrict__ Wl, const float* __restrict__ dinv,
                            float* __restrict__ Y, __half* __restrict__ Y16, int N) {
  constexpr int K = 128;
  constexpr int BM = 128;
  constexpr int WCOL = COUT / 2;
  constexpr int NFRAG = WCOL / 16;
  __shared__ unsigned short Ah[BM * K], Al[BM * K];
  __shared__ unsigned short Wsh[COUT * K], Wsl[COUT * K];

  const int tid = threadIdx.x;
  const int rb = blockIdx.x * BM;

  {
    const uint4* gh = (const uint4*)Wh;
    const uint4* gl = (const uint4*)Wl;
    for (int i = tid; i < COUT * 16; i += 512) {
      int r = i >> 4, c = i & 15;
      int byte = r * 256 + ((c * 16) ^ ((r & 7) << 4));
      *(uint4*)((char*)Wsh + byte) = gh[i];
      *(uint4*)((char*)Wsl + byte) = gl[i];
    }
  }
  {
    for (int i = tid; i < BM * 32; i += 512) {
      int r = i >> 5, c4 = i & 31;
      int g = rb + r;
      if (g < N) {
        float4 v = ((const float4*)(X + (size_t)g * K))[c4];
        ushort4 h, l;
        split4(v, h, l);
        int byte = r * 256 + ((c4 * 8) ^ ((r & 7) << 4));
        *(ushort4*)((char*)Ah + byte) = h;
        *(ushort4*)((char*)Al + byte) = l;
      }
    }
  }
  __syncthreads();

  const int wid = tid >> 6, lane = tid & 63;
  const int wm = wid & 3;
  const int wn = wid >> 2;
  const int RB = wm * 32;
  const int CB = wn * WCOL;
  const int l15 = lane & 15, l4 = lane >> 4;
  const int xs = (l15 & 7) << 4;

  f32x4 acc[2][NFRAG];
  #pragma unroll
  for (int m = 0; m < 2; ++m)
    #pragma unroll
    for (int n = 0; n < NFRAG; ++n)
      acc[m][n] = (f32x4){0.f, 0.f, 0.f, 0.f};

  #pragma unroll
  for (int ks = 0; ks < 4; ++ks) {
    const int cbx = (ks * 64 + l4 * 16) ^ xs;
    bf16x8 a0h = *(const bf16x8*)((const char*)Ah + (RB + l15) * 256 + cbx);
    bf16x8 a0l = *(const bf16x8*)((const char*)Al + (RB + l15) * 256 + cbx);
    bf16x8 a1h = *(const bf16x8*)((const char*)Ah + (RB + 16 + l15) * 256 + cbx);
    bf16x8 a1l = *(const bf16x8*)((const char*)Al + (RB + 16 + l15) * 256 + cbx);
    #pragma unroll
    for (int n = 0; n < NFRAG; ++n) {
      const int wr = CB + n * 16 + l15;
      bf16x8 bh = *(const bf16x8*)((const char*)Wsh + wr * 256 + cbx);
      bf16x8 bl = *(const bf16x8*)((const char*)Wsl + wr * 256 + cbx);
      acc[0][n] = __builtin_amdgcn_mfma_f32_16x16x32_bf16(a0h, bh, acc[0][n], 0, 0, 0);
      acc[0][n] = __builtin_amdgcn_mfma_f32_16x16x32_bf16(a0h, bl, acc[0][n], 0, 0, 0);
      acc[0][n] = __builtin_amdgcn_mfma_f32_16x16x32_bf16(a0l, bh, acc[0][n], 0, 0, 0);
      acc[1][n] = __builtin_amdgcn_mfma_f32_16x16x32_bf16(a1h, bh, acc[1][n], 0, 0, 0);
      acc[1][n] = __builtin_amdgcn_mfma_f32_16x16x32_bf16(a1h, bl, acc[1][n], 0, 0, 0);
      acc[1][n] = __builtin_amdgcn_mfma_f32_16x16x32_bf16(a1l, bh, acc[1][n], 0, 0, 0);
    }
  }

  #pragma unroll
  for (int m = 0; m < 2; ++m) {
    #pragma unroll
    for (int q = 0; q < 4; ++q) {
      int row = rb + RB + m * 16 + l4 * 4 + q;
      if (row < N) {
        float dv = dinv[row];
        float* yr = Y + (size_t)row * COUT + CB + l15;
        #pragma unroll
        for (int n = 0; n < NFRAG; ++n) {
          float val = acc[m][n][q] * dv;
          yr[n * 16] = val;
          if (Y16) Y16[(size_t)row * COUT + CB + l15 + n * 16] = __float2half(val);
        }
      }
    }
  }
}

// ---------- vector GEMM (fallback path only) ----------
template<int COUT>
__launch_bounds__(256)
__global__ void k_gemm128(const float* __restrict__ X, const float* __restrict__ W,
                          const float* __restrict__ dinv, float* __restrict__ Y, int N) {
  constexpr int K = 128;
  constexpr int CG = COUT / 8;
  constexpr int ROWS = 256 / CG;
  constexpr int XSTR = K + 4;
  __shared__ float Ws[K * COUT];
  __shared__ float Xs[ROWS * XSTR];
  const int tid = threadIdx.x;

  const float4* W4 = (const float4*)W;
  float4* Ws4 = (float4*)Ws;
  #pragma unroll
  for (int i = tid; i < K * COUT / 4; i += 256) Ws4[i] = W4[i];

  const int rb = blockIdx.x * ROWS;
  float4* Xs4 = (float4*)Xs;
  for (int i = tid; i < ROWS * (K / 4); i += 256) {
    int r = i / (K / 4), c = i % (K / 4);
    float4 v = make_float4(0.f, 0.f, 0.f, 0.f);
    if (rb + r < N) v = ((const float4*)(X + (size_t)(rb + r) * K))[c];
    Xs4[r * (XSTR / 4) + c] = v;
  }
  __syncthreads();

  const int lrow = tid / CG;
  const int cg = tid % CG;
  const int row = rb + lrow;
  float acc[8];
  #pragma unroll
  for (int j = 0; j < 8; ++j) acc[j] = 0.f;
  const float* xr = Xs + lrow * XSTR;
  #pragma unroll 4
  for (int k = 0; k < K; ++k) {
    float xv = xr[k];
    float4 w0 = Ws4[k * (COUT / 4) + cg * 2];
    float4 w1 = Ws4[k * (COUT / 4) + cg * 2 + 1];
    acc[0] = fmaf(xv, w0.x, acc[0]);
    acc[1] = fmaf(xv, w0.y, acc[1]);
    acc[2] = fmaf(xv, w0.z, acc[2]);
    acc[3] = fmaf(xv, w0.w, acc[3]);
    acc[4] = fmaf(xv, w1.x, acc[4]);
    acc[5] = fmaf(xv, w1.y, acc[5]);
    acc[6] = fmaf(xv, w1.z, acc[6]);
    acc[7] = fmaf(xv, w1.w, acc[7]);
  }
  if (row < N) {
    float ds = dinv[row];
    float4* y = (float4*)(Y + (size_t)row * COUT + cg * 8);
    y[0] = make_float4(acc[0] * ds, acc[1] * ds, acc[2] * ds, acc[3] * ds);
    y[1] = make_float4(acc[4] * ds, acc[5] * ds, acc[6] * ds, acc[7] * ds);
  }
}

// ---------- CSR gather-aggregate: one wave per (node, 64-col slice) ----------
// out = relu(dinv[node]*(self_f32 + sum nb_fp16) + bias); shfl broadcast, no LDS.
template<int C, bool H16>
__launch_bounds__(256)
__global__ void k_agg(const float* __restrict__ hsf, const __half* __restrict__ hsh,
                      const float* __restrict__ dinv, const int* __restrict__ rowptr,
                      const int* __restrict__ col, const float* __restrict__ bias,
                      float* __restrict__ out, int N) {
  constexpr int SL = C / 64;
  const int wid = blockIdx.x * 4 + (threadIdx.x >> 6);
  const int lane = threadIdx.x & 63;
  const int node = wid / SL;
  if (node >= N) return;
  const int c = (wid % SL) * 64 + lane;
  float acc = hsf[(size_t)node * C + c];
  const int beg = rowptr[node];
  const int end = rowptr[node + 1];
  for (int base = beg; base < end; base += 64) {
    int m = min(64, end - base);
    int cv = (base + lane < end) ? col[base + lane] : 0;
    for (int k = 0; k < m; ++k) {
      int nbk = __shfl(cv, k);
      if (H16) acc += __half2float(hsh[(size_t)nbk * C + c]);
      else     acc += hsf[(size_t)nbk * C + c];
    }
  }
  out[(size_t)node * C + c] = fmaxf(fmaf(dinv[node], acc, bias[c]), 0.f);
}

// ---------- fallback (atomic scatter) kernels ----------
__global__ void k_fill1(float* __restrict__ p, int n) {
  int i = blockIdx.x * blockDim.x + threadIdx.x;
  if (i < n) p[i] = 1.0f;
}
__global__ void k_deg_scatter(const int* __restrict__ dst, float* __restrict__ deg, int E) {
  int e = blockIdx.x * blockDim.x + threadIdx.x;
  if (e < E) atomicAdd(deg + dst[e], 1.0f);
}
__global__ void k_rsqrt_inplace(float* __restrict__ p, int n) {
  int i = blockIdx.x * blockDim.x + threadIdx.x;
  if (i < n) p[i] = rsqrtf(p[i]);
}
template<int C>
__global__ void k_selfinit2(const float* __restrict__ hs, const float* __restrict__ dinv,
                            float* __restrict__ agg, int N) {
  int i = blockIdx.x * blockDim.x + threadIdx.x;
  int total = N * (C / 4);
  if (i >= total) return;
  int node = i / (C / 4);
  float di = dinv[node];
  float4 v = ((const float4*)hs)[i];
  ((float4*)agg)[i] = make_float4(v.x * di, v.y * di, v.z * di, v.w * di);
}
template<int C>
__global__ void k_scatter(const float* __restrict__ hs, const float* __restrict__ dinv,
                          const int* __restrict__ src, const int* __restrict__ dst,
                          float* __restrict__ agg, int E) {
  constexpr int LPE = C / 4;
  long long t = (long long)blockIdx.x * blockDim.x + threadIdx.x;
  int e = (int)(t / LPE);
  if (e >= E) return;
  int c4 = (int)(t % LPE);
  int s = src[e], d = dst[e];
  float nd = dinv[d];
  float4 v = ((const float4*)(hs + (size_t)s * C))[c4];
  float* a = agg + (size_t)d * C + (size_t)c4 * 4;
  atomicAdd(a + 0, v.x * nd);
  atomicAdd(a + 1, v.y * nd);
  atomicAdd(a + 2, v.z * nd);
  atomicAdd(a + 3, v.w * nd);
}
template<int C>
__global__ void k_relu_bias(const float* __restrict__ agg, const float* __restrict__ b,
                            float* __restrict__ out, int N) {
  int i = blockIdx.x * blockDim.x + threadIdx.x;
  int total = N * (C / 4);
  if (i >= total) return;
  int c4 = i % (C / 4);
  float4 bb = ((const float4*)b)[c4];
  float4 v = ((const float4*)agg)[i];
  v.x = fmaxf(v.x + bb.x, 0.f);
  v.y = fmaxf(v.y + bb.y, 0.f);
  v.z = fmaxf(v.z + bb.z, 0.f);
  v.w = fmaxf(v.w + bb.w, 0.f);
  ((float4*)out)[i] = v;
}

extern "C" void kernel_launch(void* const* d_in, const int* in_sizes, int n_in,
                              void* d_out, int out_size, void* d_ws, size_t ws_size,
                              hipStream_t stream) {
  const float* x  = (const float*)d_in[0];
  const int*   ei = (const int*)d_in[1];
  const float* W1 = (const float*)d_in[2];
  const float* b1 = (const float*)d_in[3];
  const float* W2 = (const float*)d_in[4];
  const float* b2 = (const float*)d_in[5];

  const int Cin = 128, Chid = 128, Cout2 = 64;
  const int N = in_sizes[0] / Cin;
  const int E = in_sizes[1] / 2;
  const int* src = ei;
  const int* dst = ei + E;
  float* out = (float*)d_out;
  (void)n_in; (void)out_size;

  const int nbN = (N + TPB - 1) / TPB;
  const int nbE = (E + TPB - 1) / TPB;
  const int nbScan = (N + SCAN_B - 1) / SCAN_B;  // <= 1024 required
  const int nT = (N + 127) / 128;
  const int bpn = (N + NB2 - 1) / NB2;           // nodes per bucket

  auto align = [](size_t v) { return (v + 511) & ~(size_t)511; };
  char* ws = (char*)d_ws;
  size_t off = 0;
  float* dinv   = (float*)(ws + off); off += align((size_t)N * 4);
  int*   cnt    = (int*)(ws + off);   off += align((size_t)N * 4);
  int*   rowptr = (int*)(ws + off);   off += align((size_t)(N + 1) * 4);
  int*   bsum   = (int*)(ws + off);   off += align((size_t)nbScan * 4);
  unsigned short* wt1h = (unsigned short*)(ws + off); off += align((size_t)Cin * Chid * 2);
  unsigned short* wt1l = (unsigned short*)(ws + off); off += align((size_t)Cin * Chid * 2);
  unsigned short* wt2h = (unsigned short*)(ws + off); off += align((size_t)Chid * Cout2 * 2);
  unsigned short* wt2l = (unsigned short*)(ws + off); off += align((size_t)Chid * Cout2 * 2);
  int*   col    = (int*)(ws + off);   off += align((size_t)E * 4);
  float* A      = (float*)(ws + off); off += (size_t)N * Chid * 4;
  float* B      = (float*)(ws + off); off += (size_t)N * Chid * 4;
  const size_t off_csr = off;
  int*      bpos  = (int*)(ws + off);      off += align((size_t)NB2 * BPAD * 4);
  unsigned* bdata = (unsigned*)(ws + off); off += align((size_t)E * 4);
  const size_t off_fill = off;
  __half*   H16   = (__half*)(ws + off);   off += align((size_t)N * Chid * 2);
  const size_t off_fp16 = off;

  const bool csr_ok  = (off_csr <= ws_size) && (nbScan <= 1024);
  const bool fill_ok = csr_ok && (off_fill <= ws_size) && (N < (1 << 20)) && (bpn <= 256);
  const bool h16_ok  = fill_ok && (off_fp16 <= ws_size);

  if (csr_ok) {
    // ---- degree + rowptr ----
    hipMemsetAsync(cnt, 0, (size_t)N * 4, stream);
    k_hist<<<nbE, TPB, 0, stream>>>(dst, cnt, E);
    k_dinv_from_cnt<<<nbN, TPB, 0, stream>>>(cnt, dinv, N);
    k_scanA<<<nbScan, SCAN_B, 0, stream>>>(cnt, rowptr + 1, bsum, N);
    k_scanB<<<1, 1024, 0, stream>>>(bsum, nbScan);
    k_scanC<<<nbScan, SCAN_B, 0, stream>>>(rowptr, bsum, N);

    // ---- CSR col fill ----
    if (fill_ok) {
      k_bpos_init<<<NB2 / 256, 256, 0, stream>>>(rowptr, bpos, N, bpn);
      k_bfill2<<<2048, TPB, 0, stream>>>(src, dst, bpos, bdata, E, bpn);
      k_bcsr2<<<NB2, TPB, 0, stream>>>(bdata, rowptr, col, N, bpn);
    } else {
      k_copy_i32<<<nbN, TPB, 0, stream>>>(cnt, rowptr, N);
      k_fillcsr<<<nbE, TPB, 0, stream>>>(src, dst, cnt, col, E);
    }

    // ---- W prep ----
    k_prep_wt<<<(Cin * Chid + TPB - 1) / TPB, TPB, 0, stream>>>(W1, wt1h, wt1l, Cin, Chid);
    k_prep_wt<<<(Chid * Cout2 + TPB - 1) / TPB, TPB, 0, stream>>>(W2, wt2h, wt2l, Chid, Cout2);

    __half* h16p = h16_ok ? H16 : (__half*)nullptr;

    // ---- layer 1: 128 -> 128 ----
    k_gemm_mfma<128><<<nT, 512, 0, stream>>>(x, wt1h, wt1l, dinv, A, h16p, N);
    {
      int waves = N * 2, blocks = (waves + 3) / 4;
      if (h16_ok) k_agg<128, true><<<blocks, 256, 0, stream>>>(A, H16, dinv, rowptr, col, b1, B, N);
      else        k_agg<128, false><<<blocks, 256, 0, stream>>>(A, nullptr, dinv, rowptr, col, b1, B, N);
    }
    // ---- layer 2: 128 -> 64 ----
    k_gemm_mfma<64><<<nT, 512, 0, stream>>>(B, wt2h, wt2l, dinv, A, h16p, N);
    {
      int waves = N, blocks = (waves + 3) / 4;
      if (h16_ok) k_agg<64, true><<<blocks, 256, 0, stream>>>(A, H16, dinv, rowptr, col, b2, out, N);
      else        k_agg<64, false><<<blocks, 256, 0, stream>>>(A, nullptr, dinv, rowptr, col, b2, out, N);
    }
  } else {
    // ---- fallback: atomic-scatter path ----
    size_t o2 = 0;
    float* dinvF = (float*)(ws + o2); o2 += align((size_t)N * 4);
    float* AF = (float*)(ws + o2);    o2 += (size_t)N * Chid * 4;
    float* BF = (float*)(ws + o2);

    k_fill1<<<nbN, TPB, 0, stream>>>(dinvF, N);
    k_deg_scatter<<<nbE, TPB, 0, stream>>>(dst, dinvF, E);
    k_rsqrt_inplace<<<nbN, TPB, 0, stream>>>(dinvF, N);

    k_gemm128<128><<<(N + 15) / 16, 256, 0, stream>>>(x, W1, dinvF, AF, N);
    k_selfinit2<128><<<(N * 32 + TPB - 1) / TPB, TPB, 0, stream>>>(AF, dinvF, BF, N);
    {
      long long total = (long long)E * 32;
      k_scatter<128><<<(int)((total + TPB - 1) / TPB), TPB, 0, stream>>>(AF, dinvF, src, dst, BF, E);
    }
    k_relu_bias<128><<<(N * 32 + TPB - 1) / TPB, TPB, 0, stream>>>(BF, b1, AF, N);

    k_gemm128<64><<<(N + 31) / 32, 256, 0, stream>>>(AF, W2, dinvF, BF, N);
    k_selfinit2<64><<<(N * 16 + TPB - 1) / TPB, TPB, 0, stream>>>(BF, dinvF, out, N);
    {
      long long total = (long long)E * 16;
      k_scatter<64><<<(int)((total + TPB - 1) / TPB), TPB, 0, stream>>>(BF, dinvF, src, dst, out, E);
    }
    k_relu_bias<64><<<(N * 16 + TPB - 1) / TPB, TPB, 0, stream>>>(out, b2, out, N);
  }
}

// Round 6
// 411.027 us; speedup vs baseline: 1.3465x; 1.3465x over previous
//
#include <hip/hip_runtime.h>
#include <hip/hip_fp16.h>

#define TPB 256
#define SCAN_B 256
#define NB2 4096         // CSR-fill buckets
#define BPAD 16          // bucket cursor padding (ints) -> one 64B line each

typedef __attribute__((ext_vector_type(8))) short bf16x8;
typedef __attribute__((ext_vector_type(4))) float f32x4;

// ---------- fp32 -> bf16 hi/lo split ----------
__device__ inline void split1(float x, unsigned short& h, unsigned short& l) {
  unsigned xb = __float_as_uint(x);
  h = (unsigned short)(xb >> 16);
  float hf = __uint_as_float(xb & 0xFFFF0000u);
  float lf = x - hf;
  l = (unsigned short)(__float_as_uint(lf) >> 16);
}

__device__ inline void split4(const float4 v, ushort4& h, ushort4& l) {
  split1(v.x, h.x, l.x);
  split1(v.y, h.y, l.y);
  split1(v.z, h.z, l.z);
  split1(v.w, h.w, l.w);
}

// ---------- degree / rowptr ----------

__global__ void k_hist(const int* __restrict__ dst, int* __restrict__ cnt, int E) {
  int e = blockIdx.x * blockDim.x + threadIdx.x;
  if (e < E) atomicAdd(cnt + dst[e], 1);
}

__global__ void k_dinv_from_cnt(const int* __restrict__ cnt, float* __restrict__ dinv, int N) {
  int i = blockIdx.x * blockDim.x + threadIdx.x;
  if (i < N) dinv[i] = rsqrtf((float)(cnt[i] + 1));
}

__global__ void k_scanA(const int* __restrict__ cnt, int* __restrict__ rowptr1,
                        int* __restrict__ bsum, int N) {
  __shared__ int s[SCAN_B];
  int i = blockIdx.x * SCAN_B + threadIdx.x;
  int v = (i < N) ? cnt[i] : 0;
  s[threadIdx.x] = v;
  __syncthreads();
  for (int off = 1; off < SCAN_B; off <<= 1) {
    int t = (threadIdx.x >= (unsigned)off) ? s[threadIdx.x - off] : 0;
    __syncthreads();
    s[threadIdx.x] += t;
    __syncthreads();
  }
  if (i < N) rowptr1[i] = s[threadIdx.x];
  if (threadIdx.x == SCAN_B - 1) bsum[blockIdx.x] = s[SCAN_B - 1];
}

__global__ void k_scanB(int* __restrict__ bsum, int nb) {
  __shared__ int s[1024];
  int v = (threadIdx.x < (unsigned)nb) ? bsum[threadIdx.x] : 0;
  s[threadIdx.x] = v;
  __syncthreads();
  for (int off = 1; off < 1024; off <<= 1) {
    int t = (threadIdx.x >= (unsigned)off) ? s[threadIdx.x - off] : 0;
    __syncthreads();
    s[threadIdx.x] += t;
    __syncthreads();
  }
  if (threadIdx.x < (unsigned)nb) bsum[threadIdx.x] = s[threadIdx.x] - v;
}

__global__ void k_scanC(int* __restrict__ rowptr, const int* __restrict__ bsum, int N) {
  int i = blockIdx.x * SCAN_B + threadIdx.x;
  if (i < N) rowptr[i + 1] += bsum[blockIdx.x];
  if (i == 0) rowptr[0] = 0;
}

__global__ void k_copy_i32(int* __restrict__ d, const int* __restrict__ s, int n) {
  int i = blockIdx.x * blockDim.x + threadIdx.x;
  if (i < n) d[i] = s[i];
}

// ---------- bucketed CSR fill v2 ----------
// bucket b = contiguous node range [b*bpn,(b+1)*bpn) -> its bdata region is
// [rowptr[b*bpn], rowptr[min((b+1)*bpn,N)]) -- offsets derived from rowptr, no
// counting pass. Edge packed as src | local<<20 (requires N < 2^20, bpn<=256).

__global__ void k_bpos_init(const int* __restrict__ rowptr, int* __restrict__ bpos,
                            int N, int bpn) {
  int b = blockIdx.x * blockDim.x + threadIdx.x;
  if (b < NB2) bpos[b * BPAD] = rowptr[min(b * bpn, N)];
}

__global__ void k_bfill2(const int* __restrict__ src, const int* __restrict__ dst,
                         int* __restrict__ bpos, unsigned* __restrict__ bdata,
                         int E, int bpn) {
  int stride = gridDim.x * blockDim.x;
  for (int e = blockIdx.x * blockDim.x + threadIdx.x; e < E; e += stride) {
    int d = dst[e];
    int b = d / bpn;
    int p = atomicAdd(bpos + b * BPAD, 1);
    bdata[p] = (unsigned)src[e] | ((unsigned)(d - b * bpn) << 20);
  }
}

__global__ void k_bcsr2(const unsigned* __restrict__ bdata, const int* __restrict__ rowptr,
                        int* __restrict__ col, int N, int bpn) {
  __shared__ int lcnt[256];
  __shared__ int rp[257];
  const int b = blockIdx.x;
  const int nodeBase = b * bpn;
  if (nodeBase >= N) return;
  const int nn = min(bpn, N - nodeBase);
  for (int i = threadIdx.x; i < nn; i += blockDim.x) lcnt[i] = 0;
  for (int i = threadIdx.x; i <= nn; i += blockDim.x) rp[i] = rowptr[nodeBase + i];
  __syncthreads();
  const int beg = rp[0], end = rp[nn];
  for (int i = beg + threadIdx.x; i < end; i += blockDim.x) {
    unsigned w = bdata[i];
    int local = (int)(w >> 20);
    int s = atomicAdd(&lcnt[local], 1);
    col[rp[local] + s] = (int)(w & 0xFFFFFu);
  }
}

// plain fillcsr (middle-fallback only)
__global__ void k_fillcsr(const int* __restrict__ src, const int* __restrict__ dst,
                          int* __restrict__ wpos, int* __restrict__ col, int E) {
  int e = blockIdx.x * blockDim.x + threadIdx.x;
  if (e >= E) return;
  int p = atomicAdd(wpos + dst[e], 1);
  col[p] = src[e];
}

// ---------- W prep ----------
__global__ void k_prep_wt(const float* __restrict__ W, unsigned short* __restrict__ Wh,
                          unsigned short* __restrict__ Wl, int K, int C) {
  int i = blockIdx.x * blockDim.x + threadIdx.x;
  if (i >= K * C) return;
  int k = i / C, c = i % C;
  unsigned short h, l;
  split1(W[i], h, l);
  Wh[(size_t)c * K + k] = h;
  Wl[(size_t)c * K + k] = l;
}

// ---------- MFMA GEMM: Y = (X @ W) * dinv[row]; optional fp16 shadow copy ----------
template<int COUT>
__launch_bounds__(512)
__global__ void k_gemm_mfma(const float* __restrict__ X, const unsigned short* __restrict__ Wh,
                            const unsigned short* __restrict__ Wl, const float* __restrict__ dinv,
                            float* __restrict__ Y, __half* __restrict__ Y16, int N) {
  constexpr int K = 128;
  constexpr int BM = 128;
  constexpr int WCOL = COUT / 2;
  constexpr int NFRAG = WCOL / 16;
  __shared__ unsigned short Ah[BM * K], Al[BM * K];
  __shared__ unsigned short Wsh[COUT * K], Wsl[COUT * K];

  const int tid = threadIdx.x;
  const int rb = blockIdx.x * BM;

  {
    const uint4* gh = (const uint4*)Wh;
    const uint4* gl = (const uint4*)Wl;
    for (int i = tid; i < COUT * 16; i += 512) {
      int r = i >> 4, c = i & 15;
      int byte = r * 256 + ((c * 16) ^ ((r & 7) << 4));
      *(uint4*)((char*)Wsh + byte) = gh[i];
      *(uint4*)((char*)Wsl + byte) = gl[i];
    }
  }
  {
    for (int i = tid; i < BM * 32; i += 512) {
      int r = i >> 5, c4 = i & 31;
      int g = rb + r;
      if (g < N) {
        float4 v = ((const float4*)(X + (size_t)g * K))[c4];
        ushort4 h, l;
        split4(v, h, l);
        int byte = r * 256 + ((c4 * 8) ^ ((r & 7) << 4));
        *(ushort4*)((char*)Ah + byte) = h;
        *(ushort4*)((char*)Al + byte) = l;
      }
    }
  }
  __syncthreads();

  const int wid = tid >> 6, lane = tid & 63;
  const int wm = wid & 3;
  const int wn = wid >> 2;
  const int RB = wm * 32;
  const int CB = wn * WCOL;
  const int l15 = lane & 15, l4 = lane >> 4;
  const int xs = (l15 & 7) << 4;

  f32x4 acc[2][NFRAG];
  #pragma unroll
  for (int m = 0; m < 2; ++m)
    #pragma unroll
    for (int n = 0; n < NFRAG; ++n)
      acc[m][n] = (f32x4){0.f, 0.f, 0.f, 0.f};

  #pragma unroll
  for (int ks = 0; ks < 4; ++ks) {
    const int cbx = (ks * 64 + l4 * 16) ^ xs;
    bf16x8 a0h = *(const bf16x8*)((const char*)Ah + (RB + l15) * 256 + cbx);
    bf16x8 a0l = *(const bf16x8*)((const char*)Al + (RB + l15) * 256 + cbx);
    bf16x8 a1h = *(const bf16x8*)((const char*)Ah + (RB + 16 + l15) * 256 + cbx);
    bf16x8 a1l = *(const bf16x8*)((const char*)Al + (RB + 16 + l15) * 256 + cbx);
    #pragma unroll
    for (int n = 0; n < NFRAG; ++n) {
      const int wr = CB + n * 16 + l15;
      bf16x8 bh = *(const bf16x8*)((const char*)Wsh + wr * 256 + cbx);
      bf16x8 bl = *(const bf16x8*)((const char*)Wsl + wr * 256 + cbx);
      acc[0][n] = __builtin_amdgcn_mfma_f32_16x16x32_bf16(a0h, bh, acc[0][n], 0, 0, 0);
      acc[0][n] = __builtin_amdgcn_mfma_f32_16x16x32_bf16(a0h, bl, acc[0][n], 0, 0, 0);
      acc[0][n] = __builtin_amdgcn_mfma_f32_16x16x32_bf16(a0l, bh, acc[0][n], 0, 0, 0);
      acc[1][n] = __builtin_amdgcn_mfma_f32_16x16x32_bf16(a1h, bh, acc[1][n], 0, 0, 0);
      acc[1][n] = __builtin_amdgcn_mfma_f32_16x16x32_bf16(a1h, bl, acc[1][n], 0, 0, 0);
      acc[1][n] = __builtin_amdgcn_mfma_f32_16x16x32_bf16(a1l, bh, acc[1][n], 0, 0, 0);
    }
  }

  #pragma unroll
  for (int m = 0; m < 2; ++m) {
    #pragma unroll
    for (int q = 0; q < 4; ++q) {
      int row = rb + RB + m * 16 + l4 * 4 + q;
      if (row < N) {
        float dv = dinv[row];
        float* yr = Y + (size_t)row * COUT + CB + l15;
        #pragma unroll
        for (int n = 0; n < NFRAG; ++n) {
          float val = acc[m][n][q] * dv;
          yr[n * 16] = val;
          if (Y16) Y16[(size_t)row * COUT + CB + l15 + n * 16] = __float2half(val);
        }
      }
    }
  }
}

// ---------- vector GEMM (fallback path only) ----------
template<int COUT>
__launch_bounds__(256)
__global__ void k_gemm128(const float* __restrict__ X, const float* __restrict__ W,
                          const float* __restrict__ dinv, float* __restrict__ Y, int N) {
  constexpr int K = 128;
  constexpr int CG = COUT / 8;
  constexpr int ROWS = 256 / CG;
  constexpr int XSTR = K + 4;
  __shared__ float Ws[K * COUT];
  __shared__ float Xs[ROWS * XSTR];
  const int tid = threadIdx.x;

  const float4* W4 = (const float4*)W;
  float4* Ws4 = (float4*)Ws;
  #pragma unroll
  for (int i = tid; i < K * COUT / 4; i += 256) Ws4[i] = W4[i];

  const int rb = blockIdx.x * ROWS;
  float4* Xs4 = (float4*)Xs;
  for (int i = tid; i < ROWS * (K / 4); i += 256) {
    int r = i / (K / 4), c = i % (K / 4);
    float4 v = make_float4(0.f, 0.f, 0.f, 0.f);
    if (rb + r < N) v = ((const float4*)(X + (size_t)(rb + r) * K))[c];
    Xs4[r * (XSTR / 4) + c] = v;
  }
  __syncthreads();

  const int lrow = tid / CG;
  const int cg = tid % CG;
  const int row = rb + lrow;
  float acc[8];
  #pragma unroll
  for (int j = 0; j < 8; ++j) acc[j] = 0.f;
  const float* xr = Xs + lrow * XSTR;
  #pragma unroll 4
  for (int k = 0; k < K; ++k) {
    float xv = xr[k];
    float4 w0 = Ws4[k * (COUT / 4) + cg * 2];
    float4 w1 = Ws4[k * (COUT / 4) + cg * 2 + 1];
    acc[0] = fmaf(xv, w0.x, acc[0]);
    acc[1] = fmaf(xv, w0.y, acc[1]);
    acc[2] = fmaf(xv, w0.z, acc[2]);
    acc[3] = fmaf(xv, w0.w, acc[3]);
    acc[4] = fmaf(xv, w1.x, acc[4]);
    acc[5] = fmaf(xv, w1.y, acc[5]);
    acc[6] = fmaf(xv, w1.z, acc[6]);
    acc[7] = fmaf(xv, w1.w, acc[7]);
  }
  if (row < N) {
    float ds = dinv[row];
    float4* y = (float4*)(Y + (size_t)row * COUT + cg * 8);
    y[0] = make_float4(acc[0] * ds, acc[1] * ds, acc[2] * ds, acc[3] * ds);
    y[1] = make_float4(acc[4] * ds, acc[5] * ds, acc[6] * ds, acc[7] * ds);
  }
}

// ---------- CSR gather-aggregate: one block of C threads per node ----------
// (R4 structure, measured 3.9 TB/s DRAM; neighbors gathered from fp16 shadow)
template<int C, bool H16>
__launch_bounds__(C)
__global__ void k_agg(const float* __restrict__ hsf, const __half* __restrict__ hsh,
                      const float* __restrict__ dinv, const int* __restrict__ rowptr,
                      const int* __restrict__ col, const float* __restrict__ bias,
                      float* __restrict__ out, int N) {
  const int node = blockIdx.x;
  const int tid = threadIdx.x;
  float acc = hsf[(size_t)node * C + tid];
  const int beg = rowptr[node];
  const int end = rowptr[node + 1];
  __shared__ int nb[C];
  for (int base = beg; base < end; base += C) {
    int m = min(C, end - base);
    if (tid < m) nb[tid] = col[base + tid];
    __syncthreads();
    for (int k = 0; k < m; ++k) {
      if (H16) acc += __half2float(hsh[(size_t)nb[k] * C + tid]);
      else     acc += hsf[(size_t)nb[k] * C + tid];
    }
    __syncthreads();
  }
  out[(size_t)node * C + tid] = fmaxf(fmaf(dinv[node], acc, bias[tid]), 0.f);
}

// ---------- fallback (atomic scatter) kernels ----------
__global__ void k_fill1(float* __restrict__ p, int n) {
  int i = blockIdx.x * blockDim.x + threadIdx.x;
  if (i < n) p[i] = 1.0f;
}
__global__ void k_deg_scatter(const int* __restrict__ dst, float* __restrict__ deg, int E) {
  int e = blockIdx.x * blockDim.x + threadIdx.x;
  if (e < E) atomicAdd(deg + dst[e], 1.0f);
}
__global__ void k_rsqrt_inplace(float* __restrict__ p, int n) {
  int i = blockIdx.x * blockDim.x + threadIdx.x;
  if (i < n) p[i] = rsqrtf(p[i]);
}
template<int C>
__global__ void k_selfinit2(const float* __restrict__ hs, const float* __restrict__ dinv,
                            float* __restrict__ agg, int N) {
  int i = blockIdx.x * blockDim.x + threadIdx.x;
  int total = N * (C / 4);
  if (i >= total) return;
  int node = i / (C / 4);
  float di = dinv[node];
  float4 v = ((const float4*)hs)[i];
  ((float4*)agg)[i] = make_float4(v.x * di, v.y * di, v.z * di, v.w * di);
}
template<int C>
__global__ void k_scatter(const float* __restrict__ hs, const float* __restrict__ dinv,
                          const int* __restrict__ src, const int* __restrict__ dst,
                          float* __restrict__ agg, int E) {
  constexpr int LPE = C / 4;
  long long t = (long long)blockIdx.x * blockDim.x + threadIdx.x;
  int e = (int)(t / LPE);
  if (e >= E) return;
  int c4 = (int)(t % LPE);
  int s = src[e], d = dst[e];
  float nd = dinv[d];
  float4 v = ((const float4*)(hs + (size_t)s * C))[c4];
  float* a = agg + (size_t)d * C + (size_t)c4 * 4;
  atomicAdd(a + 0, v.x * nd);
  atomicAdd(a + 1, v.y * nd);
  atomicAdd(a + 2, v.z * nd);
  atomicAdd(a + 3, v.w * nd);
}
template<int C>
__global__ void k_relu_bias(const float* __restrict__ agg, const float* __restrict__ b,
                            float* __restrict__ out, int N) {
  int i = blockIdx.x * blockDim.x + threadIdx.x;
  int total = N * (C / 4);
  if (i >= total) return;
  int c4 = i % (C / 4);
  float4 bb = ((const float4*)b)[c4];
  float4 v = ((const float4*)agg)[i];
  v.x = fmaxf(v.x + bb.x, 0.f);
  v.y = fmaxf(v.y + bb.y, 0.f);
  v.z = fmaxf(v.z + bb.z, 0.f);
  v.w = fmaxf(v.w + bb.w, 0.f);
  ((float4*)out)[i] = v;
}

extern "C" void kernel_launch(void* const* d_in, const int* in_sizes, int n_in,
                              void* d_out, int out_size, void* d_ws, size_t ws_size,
                              hipStream_t stream) {
  const float* x  = (const float*)d_in[0];
  const int*   ei = (const int*)d_in[1];
  const float* W1 = (const float*)d_in[2];
  const float* b1 = (const float*)d_in[3];
  const float* W2 = (const float*)d_in[4];
  const float* b2 = (const float*)d_in[5];

  const int Cin = 128, Chid = 128, Cout2 = 64;
  const int N = in_sizes[0] / Cin;
  const int E = in_sizes[1] / 2;
  const int* src = ei;
  const int* dst = ei + E;
  float* out = (float*)d_out;
  (void)n_in; (void)out_size;

  const int nbN = (N + TPB - 1) / TPB;
  const int nbE = (E + TPB - 1) / TPB;
  const int nbScan = (N + SCAN_B - 1) / SCAN_B;  // <= 1024 required
  const int nT = (N + 127) / 128;
  const int bpn = (N + NB2 - 1) / NB2;           // nodes per bucket

  auto align = [](size_t v) { return (v + 511) & ~(size_t)511; };
  char* ws = (char*)d_ws;
  size_t off = 0;
  float* dinv   = (float*)(ws + off); off += align((size_t)N * 4);
  int*   cnt    = (int*)(ws + off);   off += align((size_t)N * 4);
  int*   rowptr = (int*)(ws + off);   off += align((size_t)(N + 1) * 4);
  int*   bsum   = (int*)(ws + off);   off += align((size_t)nbScan * 4);
  unsigned short* wt1h = (unsigned short*)(ws + off); off += align((size_t)Cin * Chid * 2);
  unsigned short* wt1l = (unsigned short*)(ws + off); off += align((size_t)Cin * Chid * 2);
  unsigned short* wt2h = (unsigned short*)(ws + off); off += align((size_t)Chid * Cout2 * 2);
  unsigned short* wt2l = (unsigned short*)(ws + off); off += align((size_t)Chid * Cout2 * 2);
  int*   col    = (int*)(ws + off);   off += align((size_t)E * 4);
  float* A      = (float*)(ws + off); off += (size_t)N * Chid * 4;
  float* B      = (float*)(ws + off); off += (size_t)N * Chid * 4;
  const size_t off_csr = off;
  int*      bpos  = (int*)(ws + off);      off += align((size_t)NB2 * BPAD * 4);
  unsigned* bdata = (unsigned*)(ws + off); off += align((size_t)E * 4);
  const size_t off_fill = off;
  __half*   H16   = (__half*)(ws + off);   off += align((size_t)N * Chid * 2);
  const size_t off_fp16 = off;

  const bool csr_ok  = (off_csr <= ws_size) && (nbScan <= 1024);
  const bool fill_ok = csr_ok && (off_fill <= ws_size) && (N < (1 << 20)) && (bpn <= 256);
  const bool h16_ok  = fill_ok && (off_fp16 <= ws_size);

  if (csr_ok) {
    // ---- degree + rowptr ----
    hipMemsetAsync(cnt, 0, (size_t)N * 4, stream);
    k_hist<<<nbE, TPB, 0, stream>>>(dst, cnt, E);
    k_dinv_from_cnt<<<nbN, TPB, 0, stream>>>(cnt, dinv, N);
    k_scanA<<<nbScan, SCAN_B, 0, stream>>>(cnt, rowptr + 1, bsum, N);
    k_scanB<<<1, 1024, 0, stream>>>(bsum, nbScan);
    k_scanC<<<nbScan, SCAN_B, 0, stream>>>(rowptr, bsum, N);

    // ---- CSR col fill ----
    if (fill_ok) {
      k_bpos_init<<<NB2 / 256, 256, 0, stream>>>(rowptr, bpos, N, bpn);
      k_bfill2<<<2048, TPB, 0, stream>>>(src, dst, bpos, bdata, E, bpn);
      k_bcsr2<<<NB2, TPB, 0, stream>>>(bdata, rowptr, col, N, bpn);
    } else {
      k_copy_i32<<<nbN, TPB, 0, stream>>>(cnt, rowptr, N);
      k_fillcsr<<<nbE, TPB, 0, stream>>>(src, dst, cnt, col, E);
    }

    // ---- W prep ----
    k_prep_wt<<<(Cin * Chid + TPB - 1) / TPB, TPB, 0, stream>>>(W1, wt1h, wt1l, Cin, Chid);
    k_prep_wt<<<(Chid * Cout2 + TPB - 1) / TPB, TPB, 0, stream>>>(W2, wt2h, wt2l, Chid, Cout2);

    __half* h16p = h16_ok ? H16 : (__half*)nullptr;

    // ---- layer 1: 128 -> 128 ----
    k_gemm_mfma<128><<<nT, 512, 0, stream>>>(x, wt1h, wt1l, dinv, A, h16p, N);
    if (h16_ok) k_agg<128, true><<<N, 128, 0, stream>>>(A, H16, dinv, rowptr, col, b1, B, N);
    else        k_agg<128, false><<<N, 128, 0, stream>>>(A, nullptr, dinv, rowptr, col, b1, B, N);
    // ---- layer 2: 128 -> 64 ----
    k_gemm_mfma<64><<<nT, 512, 0, stream>>>(B, wt2h, wt2l, dinv, A, h16p, N);
    if (h16_ok) k_agg<64, true><<<N, 64, 0, stream>>>(A, H16, dinv, rowptr, col, b2, out, N);
    else        k_agg<64, false><<<N, 64, 0, stream>>>(A, nullptr, dinv, rowptr, col, b2, out, N);
  } else {
    // ---- fallback: atomic-scatter path ----
    size_t o2 = 0;
    float* dinvF = (float*)(ws + o2); o2 += align((size_t)N * 4);
    float* AF = (float*)(ws + o2);    o2 += (size_t)N * Chid * 4;
    float* BF = (float*)(ws + o2);

    k_fill1<<<nbN, TPB, 0, stream>>>(dinvF, N);
    k_deg_scatter<<<nbE, TPB, 0, stream>>>(dst, dinvF, E);
    k_rsqrt_inplace<<<nbN, TPB, 0, stream>>>(dinvF, N);

    k_gemm128<128><<<(N + 15) / 16, 256, 0, stream>>>(x, W1, dinvF, AF, N);
    k_selfinit2<128><<<(N * 32 + TPB - 1) / TPB, TPB, 0, stream>>>(AF, dinvF, BF, N);
    {
      long long total = (long long)E * 32;
      k_scatter<128><<<(int)((total + TPB - 1) / TPB), TPB, 0, stream>>>(AF, dinvF, src, dst, BF, E);
    }
    k_relu_bias<128><<<(N * 32 + TPB - 1) / TPB, TPB, 0, stream>>>(BF, b1, AF, N);

    k_gemm128<64><<<(N + 31) / 32, 256, 0, stream>>>(AF, W2, dinvF, BF, N);
    k_selfinit2<64><<<(N * 16 + TPB - 1) / TPB, TPB, 0, stream>>>(BF, dinvF, out, N);
    {
      long long total = (long long)E * 16;
      k_scatter<64><<<(int)((total + TPB - 1) / TPB), TPB, 0, stream>>>(BF, dinvF, src, dst, out, E);
    }
    k_relu_bias<64><<<(N * 16 + TPB - 1) / TPB, TPB, 0, stream>>>(out, b2, out, N);
  }
}

// Round 7
// 364.847 us; speedup vs baseline: 1.5169x; 1.1266x over previous
//
#include <hip/hip_runtime.h>
#include <hip/hip_fp16.h>

#define TPB 256
#define SCAN_B 256

typedef __attribute__((ext_vector_type(8))) short bf16x8;
typedef __attribute__((ext_vector_type(4))) float f32x4;

// ---------- fp32 -> bf16 hi/lo split ----------
__device__ inline void split1(float x, unsigned short& h, unsigned short& l) {
  unsigned xb = __float_as_uint(x);
  h = (unsigned short)(xb >> 16);
  float hf = __uint_as_float(xb & 0xFFFF0000u);
  float lf = x - hf;
  l = (unsigned short)(__float_as_uint(lf) >> 16);
}

__device__ inline void split4(const float4 v, ushort4& h, ushort4& l) {
  split1(v.x, h.x, l.x);
  split1(v.y, h.y, l.y);
  split1(v.z, h.z, l.z);
  split1(v.w, h.w, l.w);
}

// ---------- degree / rowptr ----------

__global__ void k_hist(const int* __restrict__ dst, int* __restrict__ cnt, int E) {
  int e = blockIdx.x * blockDim.x + threadIdx.x;
  if (e < E) atomicAdd(cnt + dst[e], 1);
}

__global__ void k_dinv_from_cnt(const int* __restrict__ cnt, float* __restrict__ dinv, int N) {
  int i = blockIdx.x * blockDim.x + threadIdx.x;
  if (i < N) dinv[i] = rsqrtf((float)(cnt[i] + 1));
}

__global__ void k_scanA(const int* __restrict__ cnt, int* __restrict__ rowptr1,
                        int* __restrict__ bsum, int N) {
  __shared__ int s[SCAN_B];
  int i = blockIdx.x * SCAN_B + threadIdx.x;
  int v = (i < N) ? cnt[i] : 0;
  s[threadIdx.x] = v;
  __syncthreads();
  for (int off = 1; off < SCAN_B; off <<= 1) {
    int t = (threadIdx.x >= (unsigned)off) ? s[threadIdx.x - off] : 0;
    __syncthreads();
    s[threadIdx.x] += t;
    __syncthreads();
  }
  if (i < N) rowptr1[i] = s[threadIdx.x];
  if (threadIdx.x == SCAN_B - 1) bsum[blockIdx.x] = s[SCAN_B - 1];
}

__global__ void k_scanB(int* __restrict__ bsum, int nb) {
  __shared__ int s[1024];
  int v = (threadIdx.x < (unsigned)nb) ? bsum[threadIdx.x] : 0;
  s[threadIdx.x] = v;
  __syncthreads();
  for (int off = 1; off < 1024; off <<= 1) {
    int t = (threadIdx.x >= (unsigned)off) ? s[threadIdx.x - off] : 0;
    __syncthreads();
    s[threadIdx.x] += t;
    __syncthreads();
  }
  if (threadIdx.x < (unsigned)nb) bsum[threadIdx.x] = s[threadIdx.x] - v;
}

__global__ void k_scanC(int* __restrict__ rowptr, const int* __restrict__ bsum, int N) {
  int i = blockIdx.x * SCAN_B + threadIdx.x;
  if (i < N) rowptr[i + 1] += bsum[blockIdx.x];
  if (i == 0) rowptr[0] = 0;
}

__global__ void k_copy_i32(int* __restrict__ d, const int* __restrict__ s, int n) {
  int i = blockIdx.x * blockDim.x + threadIdx.x;
  if (i < n) d[i] = s[i];
}

// ---------- XCD-partitioned CSR fill ----------
// Block group g = blockIdx&7 (XCD round-robin heuristic) claims only edges with
// dst in its node range -> each col/wpos line is written by ONE XCD, accumulates
// in that XCD's L2, writes back once (kills the 8-13x partial-line write amp).
// Correct under any block->XCD mapping; the mapping only affects speed.
__global__ void k_fillcsr_xcd(const int* __restrict__ src, const int* __restrict__ dst,
                              int* __restrict__ wpos, int* __restrict__ col,
                              int E, int N) {
  const int g = blockIdx.x & 7;
  const int gb = blockIdx.x >> 3;
  const int gstride = (gridDim.x >> 3) * blockDim.x;
  const int lo = (int)(((long long)g * N) >> 3);
  const int hi = (int)(((long long)(g + 1) * N) >> 3);
  for (int e = gb * blockDim.x + threadIdx.x; e < E; e += gstride) {
    int d = dst[e];
    if (d >= lo && d < hi) {
      int p = atomicAdd(wpos + d, 1);
      col[p] = src[e];
    }
  }
}

// ---------- W prep ----------
__global__ void k_prep_wt(const float* __restrict__ W, unsigned short* __restrict__ Wh,
                          unsigned short* __restrict__ Wl, int K, int C) {
  int i = blockIdx.x * blockDim.x + threadIdx.x;
  if (i >= K * C) return;
  int k = i / C, c = i % C;
  unsigned short h, l;
  split1(W[i], h, l);
  Wh[(size_t)c * K + k] = h;
  Wl[(size_t)c * K + k] = l;
}

// ---------- MFMA GEMM: Y = (X @ W) * dinv[row]; optional fp16 shadow copy ----------
template<int COUT>
__launch_bounds__(512)
__global__ void k_gemm_mfma(const float* __restrict__ X, const unsigned short* __restrict__ Wh,
                            const unsigned short* __restrict__ Wl, const float* __restrict__ dinv,
                            float* __restrict__ Y, __half* __restrict__ Y16, int N) {
  constexpr int K = 128;
  constexpr int BM = 128;
  constexpr int WCOL = COUT / 2;
  constexpr int NFRAG = WCOL / 16;
  __shared__ unsigned short Ah[BM * K], Al[BM * K];
  __shared__ unsigned short Wsh[COUT * K], Wsl[COUT * K];

  const int tid = threadIdx.x;
  const int rb = blockIdx.x * BM;

  {
    const uint4* gh = (const uint4*)Wh;
    const uint4* gl = (const uint4*)Wl;
    for (int i = tid; i < COUT * 16; i += 512) {
      int r = i >> 4, c = i & 15;
      int byte = r * 256 + ((c * 16) ^ ((r & 7) << 4));
      *(uint4*)((char*)Wsh + byte) = gh[i];
      *(uint4*)((char*)Wsl + byte) = gl[i];
    }
  }
  {
    for (int i = tid; i < BM * 32; i += 512) {
      int r = i >> 5, c4 = i & 31;
      int g = rb + r;
      if (g < N) {
        float4 v = ((const float4*)(X + (size_t)g * K))[c4];
        ushort4 h, l;
        split4(v, h, l);
        int byte = r * 256 + ((c4 * 8) ^ ((r & 7) << 4));
        *(ushort4*)((char*)Ah + byte) = h;
        *(ushort4*)((char*)Al + byte) = l;
      }
    }
  }
  __syncthreads();

  const int wid = tid >> 6, lane = tid & 63;
  const int wm = wid & 3;
  const int wn = wid >> 2;
  const int RB = wm * 32;
  const int CB = wn * WCOL;
  const int l15 = lane & 15, l4 = lane >> 4;
  const int xs = (l15 & 7) << 4;

  f32x4 acc[2][NFRAG];
  #pragma unroll
  for (int m = 0; m < 2; ++m)
    #pragma unroll
    for (int n = 0; n < NFRAG; ++n)
      acc[m][n] = (f32x4){0.f, 0.f, 0.f, 0.f};

  #pragma unroll
  for (int ks = 0; ks < 4; ++ks) {
    const int cbx = (ks * 64 + l4 * 16) ^ xs;
    bf16x8 a0h = *(const bf16x8*)((const char*)Ah + (RB + l15) * 256 + cbx);
    bf16x8 a0l = *(const bf16x8*)((const char*)Al + (RB + l15) * 256 + cbx);
    bf16x8 a1h = *(const bf16x8*)((const char*)Ah + (RB + 16 + l15) * 256 + cbx);
    bf16x8 a1l = *(const bf16x8*)((const char*)Al + (RB + 16 + l15) * 256 + cbx);
    #pragma unroll
    for (int n = 0; n < NFRAG; ++n) {
      const int wr = CB + n * 16 + l15;
      bf16x8 bh = *(const bf16x8*)((const char*)Wsh + wr * 256 + cbx);
      bf16x8 bl = *(const bf16x8*)((const char*)Wsl + wr * 256 + cbx);
      acc[0][n] = __builtin_amdgcn_mfma_f32_16x16x32_bf16(a0h, bh, acc[0][n], 0, 0, 0);
      acc[0][n] = __builtin_amdgcn_mfma_f32_16x16x32_bf16(a0h, bl, acc[0][n], 0, 0, 0);
      acc[0][n] = __builtin_amdgcn_mfma_f32_16x16x32_bf16(a0l, bh, acc[0][n], 0, 0, 0);
      acc[1][n] = __builtin_amdgcn_mfma_f32_16x16x32_bf16(a1h, bh, acc[1][n], 0, 0, 0);
      acc[1][n] = __builtin_amdgcn_mfma_f32_16x16x32_bf16(a1h, bl, acc[1][n], 0, 0, 0);
      acc[1][n] = __builtin_amdgcn_mfma_f32_16x16x32_bf16(a1l, bh, acc[1][n], 0, 0, 0);
    }
  }

  #pragma unroll
  for (int m = 0; m < 2; ++m) {
    #pragma unroll
    for (int q = 0; q < 4; ++q) {
      int row = rb + RB + m * 16 + l4 * 4 + q;
      if (row < N) {
        float dv = dinv[row];
        float* yr = Y + (size_t)row * COUT + CB + l15;
        #pragma unroll
        for (int n = 0; n < NFRAG; ++n) {
          float val = acc[m][n][q] * dv;
          yr[n * 16] = val;
          if (Y16) Y16[(size_t)row * COUT + CB + l15 + n * 16] = __float2half(val);
        }
      }
    }
  }
}

// ---------- vector GEMM (fallback path only) ----------
template<int COUT>
__launch_bounds__(256)
__global__ void k_gemm128(const float* __restrict__ X, const float* __restrict__ W,
                          const float* __restrict__ dinv, float* __restrict__ Y, int N) {
  constexpr int K = 128;
  constexpr int CG = COUT / 8;
  constexpr int ROWS = 256 / CG;
  constexpr int XSTR = K + 4;
  __shared__ float Ws[K * COUT];
  __shared__ float Xs[ROWS * XSTR];
  const int tid = threadIdx.x;

  const float4* W4 = (const float4*)W;
  float4* Ws4 = (float4*)Ws;
  #pragma unroll
  for (int i = tid; i < K * COUT / 4; i += 256) Ws4[i] = W4[i];

  const int rb = blockIdx.x * ROWS;
  float4* Xs4 = (float4*)Xs;
  for (int i = tid; i < ROWS * (K / 4); i += 256) {
    int r = i / (K / 4), c = i % (K / 4);
    float4 v = make_float4(0.f, 0.f, 0.f, 0.f);
    if (rb + r < N) v = ((const float4*)(X + (size_t)(rb + r) * K))[c];
    Xs4[r * (XSTR / 4) + c] = v;
  }
  __syncthreads();

  const int lrow = tid / CG;
  const int cg = tid % CG;
  const int row = rb + lrow;
  float acc[8];
  #pragma unroll
  for (int j = 0; j < 8; ++j) acc[j] = 0.f;
  const float* xr = Xs + lrow * XSTR;
  #pragma unroll 4
  for (int k = 0; k < K; ++k) {
    float xv = xr[k];
    float4 w0 = Ws4[k * (COUT / 4) + cg * 2];
    float4 w1 = Ws4[k * (COUT / 4) + cg * 2 + 1];
    acc[0] = fmaf(xv, w0.x, acc[0]);
    acc[1] = fmaf(xv, w0.y, acc[1]);
    acc[2] = fmaf(xv, w0.z, acc[2]);
    acc[3] = fmaf(xv, w0.w, acc[3]);
    acc[4] = fmaf(xv, w1.x, acc[4]);
    acc[5] = fmaf(xv, w1.y, acc[5]);
    acc[6] = fmaf(xv, w1.z, acc[6]);
    acc[7] = fmaf(xv, w1.w, acc[7]);
  }
  if (row < N) {
    float ds = dinv[row];
    float4* y = (float4*)(Y + (size_t)row * COUT + cg * 8);
    y[0] = make_float4(acc[0] * ds, acc[1] * ds, acc[2] * ds, acc[3] * ds);
    y[1] = make_float4(acc[4] * ds, acc[5] * ds, acc[6] * ds, acc[7] * ds);
  }
}

// ---------- CSR gather-aggregate: one block of C threads per node ----------
template<int C, bool H16>
__launch_bounds__(C)
__global__ void k_agg(const float* __restrict__ hsf, const __half* __restrict__ hsh,
                      const float* __restrict__ dinv, const int* __restrict__ rowptr,
                      const int* __restrict__ col, const float* __restrict__ bias,
                      float* __restrict__ out, int N) {
  const int node = blockIdx.x;
  const int tid = threadIdx.x;
  float acc = hsf[(size_t)node * C + tid];
  const int beg = rowptr[node];
  const int end = rowptr[node + 1];
  __shared__ int nb[C];
  for (int base = beg; base < end; base += C) {
    int m = min(C, end - base);
    if (tid < m) nb[tid] = col[base + tid];
    __syncthreads();
    for (int k = 0; k < m; ++k) {
      if (H16) acc += __half2float(hsh[(size_t)nb[k] * C + tid]);
      else     acc += hsf[(size_t)nb[k] * C + tid];
    }
    __syncthreads();
  }
  out[(size_t)node * C + tid] = fmaxf(fmaf(dinv[node], acc, bias[tid]), 0.f);
}

// ---------- fallback (atomic scatter) kernels ----------
__global__ void k_fill1(float* __restrict__ p, int n) {
  int i = blockIdx.x * blockDim.x + threadIdx.x;
  if (i < n) p[i] = 1.0f;
}
__global__ void k_deg_scatter(const int* __restrict__ dst, float* __restrict__ deg, int E) {
  int e = blockIdx.x * blockDim.x + threadIdx.x;
  if (e < E) atomicAdd(deg + dst[e], 1.0f);
}
__global__ void k_rsqrt_inplace(float* __restrict__ p, int n) {
  int i = blockIdx.x * blockDim.x + threadIdx.x;
  if (i < n) p[i] = rsqrtf(p[i]);
}
template<int C>
__global__ void k_selfinit2(const float* __restrict__ hs, const float* __restrict__ dinv,
                            float* __restrict__ agg, int N) {
  int i = blockIdx.x * blockDim.x + threadIdx.x;
  int total = N * (C / 4);
  if (i >= total) return;
  int node = i / (C / 4);
  float di = dinv[node];
  float4 v = ((const float4*)hs)[i];
  ((float4*)agg)[i] = make_float4(v.x * di, v.y * di, v.z * di, v.w * di);
}
template<int C>
__global__ void k_scatter(const float* __restrict__ hs, const float* __restrict__ dinv,
                          const int* __restrict__ src, const int* __restrict__ dst,
                          float* __restrict__ agg, int E) {
  constexpr int LPE = C / 4;
  long long t = (long long)blockIdx.x * blockDim.x + threadIdx.x;
  int e = (int)(t / LPE);
  if (e >= E) return;
  int c4 = (int)(t % LPE);
  int s = src[e], d = dst[e];
  float nd = dinv[d];
  float4 v = ((const float4*)(hs + (size_t)s * C))[c4];
  float* a = agg + (size_t)d * C + (size_t)c4 * 4;
  atomicAdd(a + 0, v.x * nd);
  atomicAdd(a + 1, v.y * nd);
  atomicAdd(a + 2, v.z * nd);
  atomicAdd(a + 3, v.w * nd);
}
template<int C>
__global__ void k_relu_bias(const float* __restrict__ agg, const float* __restrict__ b,
                            float* __restrict__ out, int N) {
  int i = blockIdx.x * blockDim.x + threadIdx.x;
  int total = N * (C / 4);
  if (i >= total) return;
  int c4 = i % (C / 4);
  float4 bb = ((const float4*)b)[c4];
  float4 v = ((const float4*)agg)[i];
  v.x = fmaxf(v.x + bb.x, 0.f);
  v.y = fmaxf(v.y + bb.y, 0.f);
  v.z = fmaxf(v.z + bb.z, 0.f);
  v.w = fmaxf(v.w + bb.w, 0.f);
  ((float4*)out)[i] = v;
}

extern "C" void kernel_launch(void* const* d_in, const int* in_sizes, int n_in,
                              void* d_out, int out_size, void* d_ws, size_t ws_size,
                              hipStream_t stream) {
  const float* x  = (const float*)d_in[0];
  const int*   ei = (const int*)d_in[1];
  const float* W1 = (const float*)d_in[2];
  const float* b1 = (const float*)d_in[3];
  const float* W2 = (const float*)d_in[4];
  const float* b2 = (const float*)d_in[5];

  const int Cin = 128, Chid = 128, Cout2 = 64;
  const int N = in_sizes[0] / Cin;
  const int E = in_sizes[1] / 2;
  const int* src = ei;
  const int* dst = ei + E;
  float* out = (float*)d_out;
  (void)n_in; (void)out_size;

  const int nbN = (N + TPB - 1) / TPB;
  const int nbE = (E + TPB - 1) / TPB;
  const int nbScan = (N + SCAN_B - 1) / SCAN_B;  // <= 1024 required

  auto align = [](size_t v) { return (v + 511) & ~(size_t)511; };
  char* ws = (char*)d_ws;
  size_t off = 0;
  float* dinv   = (float*)(ws + off); off += align((size_t)N * 4);
  int*   cnt    = (int*)(ws + off);   off += align((size_t)N * 4);   // reused as wpos
  int*   rowptr = (int*)(ws + off);   off += align((size_t)(N + 1) * 4);
  int*   bsum   = (int*)(ws + off);   off += align((size_t)nbScan * 4);
  unsigned short* wt1h = (unsigned short*)(ws + off); off += align((size_t)Cin * Chid * 2);
  unsigned short* wt1l = (unsigned short*)(ws + off); off += align((size_t)Cin * Chid * 2);
  unsigned short* wt2h = (unsigned short*)(ws + off); off += align((size_t)Chid * Cout2 * 2);
  unsigned short* wt2l = (unsigned short*)(ws + off); off += align((size_t)Chid * Cout2 * 2);
  int*   col    = (int*)(ws + off);   off += align((size_t)E * 4);
  float* A      = (float*)(ws + off); off += (size_t)N * Chid * 4;
  float* B      = (float*)(ws + off); off += (size_t)N * Chid * 4;
  const size_t off_csr = off;
  __half* H16   = (__half*)(ws + off); off += align((size_t)N * Chid * 2);
  const size_t off_fp16 = off;

  const bool csr_ok = (off_csr <= ws_size) && (nbScan <= 1024);
  const bool h16_ok = csr_ok && (off_fp16 <= ws_size);

  if (csr_ok) {
    // ---- degree + rowptr ----
    hipMemsetAsync(cnt, 0, (size_t)N * 4, stream);
    k_hist<<<nbE, TPB, 0, stream>>>(dst, cnt, E);
    k_dinv_from_cnt<<<nbN, TPB, 0, stream>>>(cnt, dinv, N);
    k_scanA<<<nbScan, SCAN_B, 0, stream>>>(cnt, rowptr + 1, bsum, N);
    k_scanB<<<1, 1024, 0, stream>>>(bsum, nbScan);
    k_scanC<<<nbScan, SCAN_B, 0, stream>>>(rowptr, bsum, N);

    // ---- CSR col fill (XCD-partitioned, write-amp-free) ----
    k_copy_i32<<<nbN, TPB, 0, stream>>>(cnt, rowptr, N);   // wpos = rowptr
    k_fillcsr_xcd<<<2048, TPB, 0, stream>>>(src, dst, cnt, col, E, N);

    // ---- W prep ----
    k_prep_wt<<<(Cin * Chid + TPB - 1) / TPB, TPB, 0, stream>>>(W1, wt1h, wt1l, Cin, Chid);
    k_prep_wt<<<(Chid * Cout2 + TPB - 1) / TPB, TPB, 0, stream>>>(W2, wt2h, wt2l, Chid, Cout2);

    __half* h16p = h16_ok ? H16 : (__half*)nullptr;

    // ---- layer 1: 128 -> 128 ----
    k_gemm_mfma<128><<<(N + 127) / 128, 512, 0, stream>>>(x, wt1h, wt1l, dinv, A, h16p, N);
    if (h16_ok) k_agg<128, true><<<N, 128, 0, stream>>>(A, H16, dinv, rowptr, col, b1, B, N);
    else        k_agg<128, false><<<N, 128, 0, stream>>>(A, nullptr, dinv, rowptr, col, b1, B, N);
    // ---- layer 2: 128 -> 64 ----
    k_gemm_mfma<64><<<(N + 127) / 128, 512, 0, stream>>>(B, wt2h, wt2l, dinv, A, h16p, N);
    if (h16_ok) k_agg<64, true><<<N, 64, 0, stream>>>(A, H16, dinv, rowptr, col, b2, out, N);
    else        k_agg<64, false><<<N, 64, 0, stream>>>(A, nullptr, dinv, rowptr, col, b2, out, N);
  } else {
    // ---- fallback: atomic-scatter path ----
    size_t o2 = 0;
    float* dinvF = (float*)(ws + o2); o2 += align((size_t)N * 4);
    float* AF = (float*)(ws + o2);    o2 += (size_t)N * Chid * 4;
    float* BF = (float*)(ws + o2);

    k_fill1<<<nbN, TPB, 0, stream>>>(dinvF, N);
    k_deg_scatter<<<nbE, TPB, 0, stream>>>(dst, dinvF, E);
    k_rsqrt_inplace<<<nbN, TPB, 0, stream>>>(dinvF, N);

    k_gemm128<128><<<(N + 15) / 16, 256, 0, stream>>>(x, W1, dinvF, AF, N);
    k_selfinit2<128><<<(N * 32 + TPB - 1) / TPB, TPB, 0, stream>>>(AF, dinvF, BF, N);
    {
      long long total = (long long)E * 32;
      k_scatter<128><<<(int)((total + TPB - 1) / TPB), TPB, 0, stream>>>(AF, dinvF, src, dst, BF, E);
    }
    k_relu_bias<128><<<(N * 32 + TPB - 1) / TPB, TPB, 0, stream>>>(BF, b1, AF, N);

    k_gemm128<64><<<(N + 31) / 32, 256, 0, stream>>>(AF, W2, dinvF, BF, N);
    k_selfinit2<64><<<(N * 16 + TPB - 1) / TPB, TPB, 0, stream>>>(BF, dinvF, out, N);
    {
      long long total = (long long)E * 16;
      k_scatter<64><<<(int)((total + TPB - 1) / TPB), TPB, 0, stream>>>(BF, dinvF, src, dst, out, E);
    }
    k_relu_bias<64><<<(N * 16 + TPB - 1) / TPB, TPB, 0, stream>>>(out, b2, out, N);
  }
}

// Round 8
// 350.658 us; speedup vs baseline: 1.5783x; 1.0405x over previous
//
#include <hip/hip_runtime.h>
#include <hip/hip_fp16.h>

#define TPB 256
#define SCAN_B 256

typedef __attribute__((ext_vector_type(8))) short bf16x8;
typedef __attribute__((ext_vector_type(4))) float f32x4;

// ---------- fp32 -> bf16 hi/lo split ----------
__device__ inline void split1(float x, unsigned short& h, unsigned short& l) {
  unsigned xb = __float_as_uint(x);
  h = (unsigned short)(xb >> 16);
  float hf = __uint_as_float(xb & 0xFFFF0000u);
  float lf = x - hf;
  l = (unsigned short)(__float_as_uint(lf) >> 16);
}

__device__ inline void split4(const float4 v, ushort4& h, ushort4& l) {
  split1(v.x, h.x, l.x);
  split1(v.y, h.y, l.y);
  split1(v.z, h.z, l.z);
  split1(v.w, h.w, l.w);
}

// ---------- degree / rowptr ----------

__global__ void k_hist(const int* __restrict__ dst, int* __restrict__ cnt, int E) {
  int e = blockIdx.x * blockDim.x + threadIdx.x;
  if (e < E) atomicAdd(cnt + dst[e], 1);
}

__global__ void k_dinv_from_cnt(const int* __restrict__ cnt, float* __restrict__ dinv, int N) {
  int i = blockIdx.x * blockDim.x + threadIdx.x;
  if (i < N) dinv[i] = rsqrtf((float)(cnt[i] + 1));
}

__global__ void k_scanA(const int* __restrict__ cnt, int* __restrict__ rowptr1,
                        int* __restrict__ bsum, int N) {
  __shared__ int s[SCAN_B];
  int i = blockIdx.x * SCAN_B + threadIdx.x;
  int v = (i < N) ? cnt[i] : 0;
  s[threadIdx.x] = v;
  __syncthreads();
  for (int off = 1; off < SCAN_B; off <<= 1) {
    int t = (threadIdx.x >= (unsigned)off) ? s[threadIdx.x - off] : 0;
    __syncthreads();
    s[threadIdx.x] += t;
    __syncthreads();
  }
  if (i < N) rowptr1[i] = s[threadIdx.x];
  if (threadIdx.x == SCAN_B - 1) bsum[blockIdx.x] = s[SCAN_B - 1];
}

__global__ void k_scanB(int* __restrict__ bsum, int nb) {
  __shared__ int s[1024];
  int v = (threadIdx.x < (unsigned)nb) ? bsum[threadIdx.x] : 0;
  s[threadIdx.x] = v;
  __syncthreads();
  for (int off = 1; off < 1024; off <<= 1) {
    int t = (threadIdx.x >= (unsigned)off) ? s[threadIdx.x - off] : 0;
    __syncthreads();
    s[threadIdx.x] += t;
    __syncthreads();
  }
  if (threadIdx.x < (unsigned)nb) bsum[threadIdx.x] = s[threadIdx.x] - v;
}

__global__ void k_scanC(int* __restrict__ rowptr, const int* __restrict__ bsum, int N) {
  int i = blockIdx.x * SCAN_B + threadIdx.x;
  if (i < N) rowptr[i + 1] += bsum[blockIdx.x];
  if (i == 0) rowptr[0] = 0;
}

__global__ void k_copy_i32(int* __restrict__ d, const int* __restrict__ s, int n) {
  int i = blockIdx.x * blockDim.x + threadIdx.x;
  if (i < n) d[i] = s[i];
}

// ---------- XCD-partitioned CSR fill ----------
__global__ void k_fillcsr_xcd(const int* __restrict__ src, const int* __restrict__ dst,
                              int* __restrict__ wpos, int* __restrict__ col,
                              int E, int N) {
  const int g = blockIdx.x & 7;
  const int gb = blockIdx.x >> 3;
  const int gstride = (gridDim.x >> 3) * blockDim.x;
  const int lo = (int)(((long long)g * N) >> 3);
  const int hi = (int)(((long long)(g + 1) * N) >> 3);
  for (int e = gb * blockDim.x + threadIdx.x; e < E; e += gstride) {
    int d = dst[e];
    if (d >= lo && d < hi) {
      int p = atomicAdd(wpos + d, 1);
      col[p] = src[e];
    }
  }
}

// ---------- W prep ----------
__global__ void k_prep_wt(const float* __restrict__ W, unsigned short* __restrict__ Wh,
                          unsigned short* __restrict__ Wl, int K, int C) {
  int i = blockIdx.x * blockDim.x + threadIdx.x;
  if (i >= K * C) return;
  int k = i / C, c = i % C;
  unsigned short h, l;
  split1(W[i], h, l);
  Wh[(size_t)c * K + k] = h;
  Wl[(size_t)c * K + k] = l;
}

// ---------- MFMA GEMM: Y = (X @ W) * dinv[row]; optional fp16 shadow copy ----------
template<int COUT>
__launch_bounds__(512)
__global__ void k_gemm_mfma(const float* __restrict__ X, const unsigned short* __restrict__ Wh,
                            const unsigned short* __restrict__ Wl, const float* __restrict__ dinv,
                            float* __restrict__ Y, __half* __restrict__ Y16, int N) {
  constexpr int K = 128;
  constexpr int BM = 128;
  constexpr int WCOL = COUT / 2;
  constexpr int NFRAG = WCOL / 16;
  __shared__ unsigned short Ah[BM * K], Al[BM * K];
  __shared__ unsigned short Wsh[COUT * K], Wsl[COUT * K];

  const int tid = threadIdx.x;
  const int rb = blockIdx.x * BM;

  {
    const uint4* gh = (const uint4*)Wh;
    const uint4* gl = (const uint4*)Wl;
    for (int i = tid; i < COUT * 16; i += 512) {
      int r = i >> 4, c = i & 15;
      int byte = r * 256 + ((c * 16) ^ ((r & 7) << 4));
      *(uint4*)((char*)Wsh + byte) = gh[i];
      *(uint4*)((char*)Wsl + byte) = gl[i];
    }
  }
  {
    for (int i = tid; i < BM * 32; i += 512) {
      int r = i >> 5, c4 = i & 31;
      int g = rb + r;
      if (g < N) {
        float4 v = ((const float4*)(X + (size_t)g * K))[c4];
        ushort4 h, l;
        split4(v, h, l);
        int byte = r * 256 + ((c4 * 8) ^ ((r & 7) << 4));
        *(ushort4*)((char*)Ah + byte) = h;
        *(ushort4*)((char*)Al + byte) = l;
      }
    }
  }
  __syncthreads();

  const int wid = tid >> 6, lane = tid & 63;
  const int wm = wid & 3;
  const int wn = wid >> 2;
  const int RB = wm * 32;
  const int CB = wn * WCOL;
  const int l15 = lane & 15, l4 = lane >> 4;
  const int xs = (l15 & 7) << 4;

  f32x4 acc[2][NFRAG];
  #pragma unroll
  for (int m = 0; m < 2; ++m)
    #pragma unroll
    for (int n = 0; n < NFRAG; ++n)
      acc[m][n] = (f32x4){0.f, 0.f, 0.f, 0.f};

  #pragma unroll
  for (int ks = 0; ks < 4; ++ks) {
    const int cbx = (ks * 64 + l4 * 16) ^ xs;
    bf16x8 a0h = *(const bf16x8*)((const char*)Ah + (RB + l15) * 256 + cbx);
    bf16x8 a0l = *(const bf16x8*)((const char*)Al + (RB + l15) * 256 + cbx);
    bf16x8 a1h = *(const bf16x8*)((const char*)Ah + (RB + 16 + l15) * 256 + cbx);
    bf16x8 a1l = *(const bf16x8*)((const char*)Al + (RB + 16 + l15) * 256 + cbx);
    #pragma unroll
    for (int n = 0; n < NFRAG; ++n) {
      const int wr = CB + n * 16 + l15;
      bf16x8 bh = *(const bf16x8*)((const char*)Wsh + wr * 256 + cbx);
      bf16x8 bl = *(const bf16x8*)((const char*)Wsl + wr * 256 + cbx);
      acc[0][n] = __builtin_amdgcn_mfma_f32_16x16x32_bf16(a0h, bh, acc[0][n], 0, 0, 0);
      acc[0][n] = __builtin_amdgcn_mfma_f32_16x16x32_bf16(a0h, bl, acc[0][n], 0, 0, 0);
      acc[0][n] = __builtin_amdgcn_mfma_f32_16x16x32_bf16(a0l, bh, acc[0][n], 0, 0, 0);
      acc[1][n] = __builtin_amdgcn_mfma_f32_16x16x32_bf16(a1h, bh, acc[1][n], 0, 0, 0);
      acc[1][n] = __builtin_amdgcn_mfma_f32_16x16x32_bf16(a1h, bl, acc[1][n], 0, 0, 0);
      acc[1][n] = __builtin_amdgcn_mfma_f32_16x16x32_bf16(a1l, bh, acc[1][n], 0, 0, 0);
    }
  }

  #pragma unroll
  for (int m = 0; m < 2; ++m) {
    #pragma unroll
    for (int q = 0; q < 4; ++q) {
      int row = rb + RB + m * 16 + l4 * 4 + q;
      if (row < N) {
        float dv = dinv[row];
        float* yr = Y + (size_t)row * COUT + CB + l15;
        #pragma unroll
        for (int n = 0; n < NFRAG; ++n) {
          float val = acc[m][n][q] * dv;
          yr[n * 16] = val;
          if (Y16) Y16[(size_t)row * COUT + CB + l15 + n * 16] = __float2half(val);
        }
      }
    }
  }
}

// ---------- vector GEMM (fallback path only) ----------
template<int COUT>
__launch_bounds__(256)
__global__ void k_gemm128(const float* __restrict__ X, const float* __restrict__ W,
                          const float* __restrict__ dinv, float* __restrict__ Y, int N) {
  constexpr int K = 128;
  constexpr int CG = COUT / 8;
  constexpr int ROWS = 256 / CG;
  constexpr int XSTR = K + 4;
  __shared__ float Ws[K * COUT];
  __shared__ float Xs[ROWS * XSTR];
  const int tid = threadIdx.x;

  const float4* W4 = (const float4*)W;
  float4* Ws4 = (float4*)Ws;
  #pragma unroll
  for (int i = tid; i < K * COUT / 4; i += 256) Ws4[i] = W4[i];

  const int rb = blockIdx.x * ROWS;
  float4* Xs4 = (float4*)Xs;
  for (int i = tid; i < ROWS * (K / 4); i += 256) {
    int r = i / (K / 4), c = i % (K / 4);
    float4 v = make_float4(0.f, 0.f, 0.f, 0.f);
    if (rb + r < N) v = ((const float4*)(X + (size_t)(rb + r) * K))[c];
    Xs4[r * (XSTR / 4) + c] = v;
  }
  __syncthreads();

  const int lrow = tid / CG;
  const int cg = tid % CG;
  const int row = rb + lrow;
  float acc[8];
  #pragma unroll
  for (int j = 0; j < 8; ++j) acc[j] = 0.f;
  const float* xr = Xs + lrow * XSTR;
  #pragma unroll 4
  for (int k = 0; k < K; ++k) {
    float xv = xr[k];
    float4 w0 = Ws4[k * (COUT / 4) + cg * 2];
    float4 w1 = Ws4[k * (COUT / 4) + cg * 2 + 1];
    acc[0] = fmaf(xv, w0.x, acc[0]);
    acc[1] = fmaf(xv, w0.y, acc[1]);
    acc[2] = fmaf(xv, w0.z, acc[2]);
    acc[3] = fmaf(xv, w0.w, acc[3]);
    acc[4] = fmaf(xv, w1.x, acc[4]);
    acc[5] = fmaf(xv, w1.y, acc[5]);
    acc[6] = fmaf(xv, w1.z, acc[6]);
    acc[7] = fmaf(xv, w1.w, acc[7]);
  }
  if (row < N) {
    float ds = dinv[row];
    float4* y = (float4*)(Y + (size_t)row * COUT + cg * 8);
    y[0] = make_float4(acc[0] * ds, acc[1] * ds, acc[2] * ds, acc[3] * ds);
    y[1] = make_float4(acc[4] * ds, acc[5] * ds, acc[6] * ds, acc[7] * ds);
  }
}

// ---------- vectorized CSR gather-aggregate: one WAVE per node ----------
// Lanes = (C/8 row-slices) x (NG neighbor groups). Each lane does a uint4
// (8-half, 16B) gather -> 1KB per wave instruction, NG neighbor rows in
// flight per issue slot. __shfl_xor folds neighbor groups; epilogue fuses
// self(f32) + dinv + bias + relu with float4 stores.
template<int C>
__launch_bounds__(256)
__global__ void k_aggv(const float* __restrict__ hsf, const __half* __restrict__ hsh,
                       const float* __restrict__ dinv, const int* __restrict__ rowptr,
                       const int* __restrict__ col, const float* __restrict__ bias,
                       float* __restrict__ out, int N) {
  constexpr int LPR = C / 8;           // lanes per row: 16 (C=128) / 8 (C=64)
  constexpr int NG = 64 / LPR;         // neighbors per wave instruction: 4 / 8
  const int node = blockIdx.x * 4 + (threadIdx.x >> 6);
  if (node >= N) return;
  const int lane = threadIdx.x & 63;
  const int i = lane % LPR;            // row-slice (cols 8i..8i+7)
  const int j = lane / LPR;            // neighbor group
  const int beg = rowptr[node], end = rowptr[node + 1];

  float acc[8];
  #pragma unroll
  for (int q = 0; q < 8; ++q) acc[q] = 0.f;

  for (int k = beg; k < end; k += NG) {
    int slot = k + j;
    bool valid = slot < end;
    int nb = col[valid ? slot : end - 1];
    uint4 v = *(const uint4*)((const char*)hsh + ((size_t)nb * C + i * 8) * 2);
    float s = valid ? 1.f : 0.f;
    const __half2* h2 = (const __half2*)&v;
    #pragma unroll
    for (int q = 0; q < 4; ++q) {
      float2 f = __half22float2(h2[q]);
      acc[2 * q]     = fmaf(s, f.x, acc[2 * q]);
      acc[2 * q + 1] = fmaf(s, f.y, acc[2 * q + 1]);
    }
  }

  #pragma unroll
  for (int off = LPR; off < 64; off <<= 1)
    #pragma unroll
    for (int q = 0; q < 8; ++q)
      acc[q] += __shfl_xor(acc[q], off);

  if (j < 2) {
    const float dv = dinv[node];
    const int f4 = 2 * i + j;          // float4 index within row
    float4 sv = ((const float4*)(hsf + (size_t)node * C))[f4];
    float4 bb = ((const float4*)bias)[f4];
    float r0 = acc[4 * j + 0], r1 = acc[4 * j + 1];
    float r2 = acc[4 * j + 2], r3 = acc[4 * j + 3];
    float4 o;
    o.x = fmaxf(fmaf(dv, sv.x + r0, bb.x), 0.f);
    o.y = fmaxf(fmaf(dv, sv.y + r1, bb.y), 0.f);
    o.z = fmaxf(fmaf(dv, sv.z + r2, bb.z), 0.f);
    o.w = fmaxf(fmaf(dv, sv.w + r3, bb.w), 0.f);
    ((float4*)(out + (size_t)node * C))[f4] = o;
  }
}

// scalar fallback agg (no-fp16 path)
template<int C>
__launch_bounds__(C)
__global__ void k_agg(const float* __restrict__ hsf, const float* __restrict__ dinv,
                      const int* __restrict__ rowptr, const int* __restrict__ col,
                      const float* __restrict__ bias, float* __restrict__ out, int N) {
  const int node = blockIdx.x;
  const int tid = threadIdx.x;
  float acc = hsf[(size_t)node * C + tid];
  const int beg = rowptr[node];
  const int end = rowptr[node + 1];
  __shared__ int nb[C];
  for (int base = beg; base < end; base += C) {
    int m = min(C, end - base);
    if (tid < m) nb[tid] = col[base + tid];
    __syncthreads();
    for (int k = 0; k < m; ++k) acc += hsf[(size_t)nb[k] * C + tid];
    __syncthreads();
  }
  out[(size_t)node * C + tid] = fmaxf(fmaf(dinv[node], acc, bias[tid]), 0.f);
}

// ---------- fallback (atomic scatter) kernels ----------
__global__ void k_fill1(float* __restrict__ p, int n) {
  int i = blockIdx.x * blockDim.x + threadIdx.x;
  if (i < n) p[i] = 1.0f;
}
__global__ void k_deg_scatter(const int* __restrict__ dst, float* __restrict__ deg, int E) {
  int e = blockIdx.x * blockDim.x + threadIdx.x;
  if (e < E) atomicAdd(deg + dst[e], 1.0f);
}
__global__ void k_rsqrt_inplace(float* __restrict__ p, int n) {
  int i = blockIdx.x * blockDim.x + threadIdx.x;
  if (i < n) p[i] = rsqrtf(p[i]);
}
template<int C>
__global__ void k_selfinit2(const float* __restrict__ hs, const float* __restrict__ dinv,
                            float* __restrict__ agg, int N) {
  int i = blockIdx.x * blockDim.x + threadIdx.x;
  int total = N * (C / 4);
  if (i >= total) return;
  int node = i / (C / 4);
  float di = dinv[node];
  float4 v = ((const float4*)hs)[i];
  ((float4*)agg)[i] = make_float4(v.x * di, v.y * di, v.z * di, v.w * di);
}
template<int C>
__global__ void k_scatter(const float* __restrict__ hs, const float* __restrict__ dinv,
                          const int* __restrict__ src, const int* __restrict__ dst,
                          float* __restrict__ agg, int E) {
  constexpr int LPE = C / 4;
  long long t = (long long)blockIdx.x * blockDim.x + threadIdx.x;
  int e = (int)(t / LPE);
  if (e >= E) return;
  int c4 = (int)(t % LPE);
  int s = src[e], d = dst[e];
  float nd = dinv[d];
  float4 v = ((const float4*)(hs + (size_t)s * C))[c4];
  float* a = agg + (size_t)d * C + (size_t)c4 * 4;
  atomicAdd(a + 0, v.x * nd);
  atomicAdd(a + 1, v.y * nd);
  atomicAdd(a + 2, v.z * nd);
  atomicAdd(a + 3, v.w * nd);
}
template<int C>
__global__ void k_relu_bias(const float* __restrict__ agg, const float* __restrict__ b,
                            float* __restrict__ out, int N) {
  int i = blockIdx.x * blockDim.x + threadIdx.x;
  int total = N * (C / 4);
  if (i >= total) return;
  int c4 = i % (C / 4);
  float4 bb = ((const float4*)b)[c4];
  float4 v = ((const float4*)agg)[i];
  v.x = fmaxf(v.x + bb.x, 0.f);
  v.y = fmaxf(v.y + bb.y, 0.f);
  v.z = fmaxf(v.z + bb.z, 0.f);
  v.w = fmaxf(v.w + bb.w, 0.f);
  ((float4*)out)[i] = v;
}

extern "C" void kernel_launch(void* const* d_in, const int* in_sizes, int n_in,
                              void* d_out, int out_size, void* d_ws, size_t ws_size,
                              hipStream_t stream) {
  const float* x  = (const float*)d_in[0];
  const int*   ei = (const int*)d_in[1];
  const float* W1 = (const float*)d_in[2];
  const float* b1 = (const float*)d_in[3];
  const float* W2 = (const float*)d_in[4];
  const float* b2 = (const float*)d_in[5];

  const int Cin = 128, Chid = 128, Cout2 = 64;
  const int N = in_sizes[0] / Cin;
  const int E = in_sizes[1] / 2;
  const int* src = ei;
  const int* dst = ei + E;
  float* out = (float*)d_out;
  (void)n_in; (void)out_size;

  const int nbN = (N + TPB - 1) / TPB;
  const int nbE = (E + TPB - 1) / TPB;
  const int nbScan = (N + SCAN_B - 1) / SCAN_B;  // <= 1024 required

  auto align = [](size_t v) { return (v + 511) & ~(size_t)511; };
  char* ws = (char*)d_ws;
  size_t off = 0;
  float* dinv   = (float*)(ws + off); off += align((size_t)N * 4);
  int*   cnt    = (int*)(ws + off);   off += align((size_t)N * 4);   // reused as wpos
  int*   rowptr = (int*)(ws + off);   off += align((size_t)(N + 1) * 4);
  int*   bsum   = (int*)(ws + off);   off += align((size_t)nbScan * 4);
  unsigned short* wt1h = (unsigned short*)(ws + off); off += align((size_t)Cin * Chid * 2);
  unsigned short* wt1l = (unsigned short*)(ws + off); off += align((size_t)Cin * Chid * 2);
  unsigned short* wt2h = (unsigned short*)(ws + off); off += align((size_t)Chid * Cout2 * 2);
  unsigned short* wt2l = (unsigned short*)(ws + off); off += align((size_t)Chid * Cout2 * 2);
  int*   col    = (int*)(ws + off);   off += align((size_t)E * 4);
  float* A      = (float*)(ws + off); off += (size_t)N * Chid * 4;
  float* B      = (float*)(ws + off); off += (size_t)N * Chid * 4;
  const size_t off_csr = off;
  __half* H16   = (__half*)(ws + off); off += align((size_t)N * Chid * 2);
  const size_t off_fp16 = off;

  const bool csr_ok = (off_csr <= ws_size) && (nbScan <= 1024);
  const bool h16_ok = csr_ok && (off_fp16 <= ws_size);

  if (csr_ok) {
    // ---- degree + rowptr ----
    hipMemsetAsync(cnt, 0, (size_t)N * 4, stream);
    k_hist<<<nbE, TPB, 0, stream>>>(dst, cnt, E);
    k_dinv_from_cnt<<<nbN, TPB, 0, stream>>>(cnt, dinv, N);
    k_scanA<<<nbScan, SCAN_B, 0, stream>>>(cnt, rowptr + 1, bsum, N);
    k_scanB<<<1, 1024, 0, stream>>>(bsum, nbScan);
    k_scanC<<<nbScan, SCAN_B, 0, stream>>>(rowptr, bsum, N);

    // ---- CSR col fill (XCD-partitioned, write-amp-free) ----
    k_copy_i32<<<nbN, TPB, 0, stream>>>(cnt, rowptr, N);   // wpos = rowptr
    k_fillcsr_xcd<<<2048, TPB, 0, stream>>>(src, dst, cnt, col, E, N);

    // ---- W prep ----
    k_prep_wt<<<(Cin * Chid + TPB - 1) / TPB, TPB, 0, stream>>>(W1, wt1h, wt1l, Cin, Chid);
    k_prep_wt<<<(Chid * Cout2 + TPB - 1) / TPB, TPB, 0, stream>>>(W2, wt2h, wt2l, Chid, Cout2);

    __half* h16p = h16_ok ? H16 : (__half*)nullptr;

    // ---- layer 1: 128 -> 128 ----
    k_gemm_mfma<128><<<(N + 127) / 128, 512, 0, stream>>>(x, wt1h, wt1l, dinv, A, h16p, N);
    if (h16_ok) k_aggv<128><<<(N + 3) / 4, 256, 0, stream>>>(A, H16, dinv, rowptr, col, b1, B, N);
    else        k_agg<128><<<N, 128, 0, stream>>>(A, dinv, rowptr, col, b1, B, N);
    // ---- layer 2: 128 -> 64 ----
    k_gemm_mfma<64><<<(N + 127) / 128, 512, 0, stream>>>(B, wt2h, wt2l, dinv, A, h16p, N);
    if (h16_ok) k_aggv<64><<<(N + 3) / 4, 256, 0, stream>>>(A, H16, dinv, rowptr, col, b2, out, N);
    else        k_agg<64><<<N, 64, 0, stream>>>(A, dinv, rowptr, col, b2, out, N);
  } else {
    // ---- fallback: atomic-scatter path ----
    size_t o2 = 0;
    float* dinvF = (float*)(ws + o2); o2 += align((size_t)N * 4);
    float* AF = (float*)(ws + o2);    o2 += (size_t)N * Chid * 4;
    float* BF = (float*)(ws + o2);

    k_fill1<<<nbN, TPB, 0, stream>>>(dinvF, N);
    k_deg_scatter<<<nbE, TPB, 0, stream>>>(dst, dinvF, E);
    k_rsqrt_inplace<<<nbN, TPB, 0, stream>>>(dinvF, N);

    k_gemm128<128><<<(N + 15) / 16, 256, 0, stream>>>(x, W1, dinvF, AF, N);
    k_selfinit2<128><<<(N * 32 + TPB - 1) / TPB, TPB, 0, stream>>>(AF, dinvF, BF, N);
    {
      long long total = (long long)E * 32;
      k_scatter<128><<<(int)((total + TPB - 1) / TPB), TPB, 0, stream>>>(AF, dinvF, src, dst, BF, E);
    }
    k_relu_bias<128><<<(N * 32 + TPB - 1) / TPB, TPB, 0, stream>>>(BF, b1, AF, N);

    k_gemm128<64><<<(N + 31) / 32, 256, 0, stream>>>(AF, W2, dinvF, BF, N);
    k_selfinit2<64><<<(N * 16 + TPB - 1) / TPB, TPB, 0, stream>>>(BF, dinvF, out, N);
    {
      long long total = (long long)E * 16;
      k_scatter<64><<<(int)((total + TPB - 1) / TPB), TPB, 0, stream>>>(BF, dinvF, src, dst, out, E);
    }
    k_relu_bias<64><<<(N * 16 + TPB - 1) / TPB, TPB, 0, stream>>>(out, b2, out, N);
  }
}

// Round 9
// 339.854 us; speedup vs baseline: 1.6285x; 1.0318x over previous
//
#include <hip/hip_runtime.h>
#include <hip/hip_fp16.h>

#define TPB 256
#define SCAN_B 256

typedef __attribute__((ext_vector_type(8))) short bf16x8;
typedef __attribute__((ext_vector_type(4))) float f32x4;

// ---------- fp32 -> bf16 hi/lo split ----------
__device__ inline void split1(float x, unsigned short& h, unsigned short& l) {
  unsigned xb = __float_as_uint(x);
  h = (unsigned short)(xb >> 16);
  float hf = __uint_as_float(xb & 0xFFFF0000u);
  float lf = x - hf;
  l = (unsigned short)(__float_as_uint(lf) >> 16);
}

__device__ inline void split4(const float4 v, ushort4& h, ushort4& l) {
  split1(v.x, h.x, l.x);
  split1(v.y, h.y, l.y);
  split1(v.z, h.z, l.z);
  split1(v.w, h.w, l.w);
}

// ---------- degree / rowptr ----------

// XCD-partitioned histogram: block group g=blockIdx&7 owns nodes [lo,hi) ->
// each cnt line is atomically updated by ONE XCD (no cross-XCD line bounce).
__global__ void k_hist_xcd(const int* __restrict__ dst, int* __restrict__ cnt,
                           int E, int N) {
  const int g = blockIdx.x & 7;
  const int gb = blockIdx.x >> 3;
  const int gstride = (gridDim.x >> 3) * blockDim.x;
  const int lo = (int)(((long long)g * N) >> 3);
  const int hi = (int)(((long long)(g + 1) * N) >> 3);
  for (int e = gb * blockDim.x + threadIdx.x; e < E; e += gstride) {
    int d = dst[e];
    if (d >= lo && d < hi) atomicAdd(cnt + d, 1);
  }
}

__global__ void k_dinv_from_cnt(const int* __restrict__ cnt, float* __restrict__ dinv, int N) {
  int i = blockIdx.x * blockDim.x + threadIdx.x;
  if (i < N) dinv[i] = rsqrtf((float)(cnt[i] + 1));
}

__global__ void k_scanA(const int* __restrict__ cnt, int* __restrict__ rowptr1,
                        int* __restrict__ bsum, int N) {
  __shared__ int s[SCAN_B];
  int i = blockIdx.x * SCAN_B + threadIdx.x;
  int v = (i < N) ? cnt[i] : 0;
  s[threadIdx.x] = v;
  __syncthreads();
  for (int off = 1; off < SCAN_B; off <<= 1) {
    int t = (threadIdx.x >= (unsigned)off) ? s[threadIdx.x - off] : 0;
    __syncthreads();
    s[threadIdx.x] += t;
    __syncthreads();
  }
  if (i < N) rowptr1[i] = s[threadIdx.x];
  if (threadIdx.x == SCAN_B - 1) bsum[blockIdx.x] = s[SCAN_B - 1];
}

__global__ void k_scanB(int* __restrict__ bsum, int nb) {
  __shared__ int s[1024];
  int v = (threadIdx.x < (unsigned)nb) ? bsum[threadIdx.x] : 0;
  s[threadIdx.x] = v;
  __syncthreads();
  for (int off = 1; off < 1024; off <<= 1) {
    int t = (threadIdx.x >= (unsigned)off) ? s[threadIdx.x - off] : 0;
    __syncthreads();
    s[threadIdx.x] += t;
    __syncthreads();
  }
  if (threadIdx.x < (unsigned)nb) bsum[threadIdx.x] = s[threadIdx.x] - v;
}

// finalizes rowptr AND initializes the fill cursors (wpos = rowptr)
__global__ void k_scanC(int* __restrict__ rowptr, int* __restrict__ wpos,
                        const int* __restrict__ bsum, int N) {
  int i = blockIdx.x * SCAN_B + threadIdx.x;
  if (i < N) {
    int v = rowptr[i + 1] + bsum[blockIdx.x];
    rowptr[i + 1] = v;
    if (i + 1 < N) wpos[i + 1] = v;
  }
  if (i == 0) { rowptr[0] = 0; wpos[0] = 0; }
}

// ---------- XCD-partitioned CSR fill ----------
__global__ void k_fillcsr_xcd(const int* __restrict__ src, const int* __restrict__ dst,
                              int* __restrict__ wpos, int* __restrict__ col,
                              int E, int N) {
  const int g = blockIdx.x & 7;
  const int gb = blockIdx.x >> 3;
  const int gstride = (gridDim.x >> 3) * blockDim.x;
  const int lo = (int)(((long long)g * N) >> 3);
  const int hi = (int)(((long long)(g + 1) * N) >> 3);
  for (int e = gb * blockDim.x + threadIdx.x; e < E; e += gstride) {
    int d = dst[e];
    if (d >= lo && d < hi) {
      int p = atomicAdd(wpos + d, 1);
      col[p] = src[e];
    }
  }
}

// ---------- W prep ----------
__global__ void k_prep_wt(const float* __restrict__ W, unsigned short* __restrict__ Wh,
                          unsigned short* __restrict__ Wl, int K, int C) {
  int i = blockIdx.x * blockDim.x + threadIdx.x;
  if (i >= K * C) return;
  int k = i / C, c = i % C;
  unsigned short h, l;
  split1(W[i], h, l);
  Wh[(size_t)c * K + k] = h;
  Wl[(size_t)c * K + k] = l;
}

// ---------- MFMA GEMM: Y = (X @ W) * dinv[row]; optional fp16 shadow copy ----------
template<int COUT>
__launch_bounds__(512)
__global__ void k_gemm_mfma(const float* __restrict__ X, const unsigned short* __restrict__ Wh,
                            const unsigned short* __restrict__ Wl, const float* __restrict__ dinv,
                            float* __restrict__ Y, __half* __restrict__ Y16, int N) {
  constexpr int K = 128;
  constexpr int BM = 128;
  constexpr int WCOL = COUT / 2;
  constexpr int NFRAG = WCOL / 16;
  __shared__ unsigned short Ah[BM * K], Al[BM * K];
  __shared__ unsigned short Wsh[COUT * K], Wsl[COUT * K];

  const int tid = threadIdx.x;
  const int rb = blockIdx.x * BM;

  {
    const uint4* gh = (const uint4*)Wh;
    const uint4* gl = (const uint4*)Wl;
    for (int i = tid; i < COUT * 16; i += 512) {
      int r = i >> 4, c = i & 15;
      int byte = r * 256 + ((c * 16) ^ ((r & 7) << 4));
      *(uint4*)((char*)Wsh + byte) = gh[i];
      *(uint4*)((char*)Wsl + byte) = gl[i];
    }
  }
  {
    for (int i = tid; i < BM * 32; i += 512) {
      int r = i >> 5, c4 = i & 31;
      int g = rb + r;
      if (g < N) {
        float4 v = ((const float4*)(X + (size_t)g * K))[c4];
        ushort4 h, l;
        split4(v, h, l);
        int byte = r * 256 + ((c4 * 8) ^ ((r & 7) << 4));
        *(ushort4*)((char*)Ah + byte) = h;
        *(ushort4*)((char*)Al + byte) = l;
      }
    }
  }
  __syncthreads();

  const int wid = tid >> 6, lane = tid & 63;
  const int wm = wid & 3;
  const int wn = wid >> 2;
  const int RB = wm * 32;
  const int CB = wn * WCOL;
  const int l15 = lane & 15, l4 = lane >> 4;
  const int xs = (l15 & 7) << 4;

  f32x4 acc[2][NFRAG];
  #pragma unroll
  for (int m = 0; m < 2; ++m)
    #pragma unroll
    for (int n = 0; n < NFRAG; ++n)
      acc[m][n] = (f32x4){0.f, 0.f, 0.f, 0.f};

  #pragma unroll
  for (int ks = 0; ks < 4; ++ks) {
    const int cbx = (ks * 64 + l4 * 16) ^ xs;
    bf16x8 a0h = *(const bf16x8*)((const char*)Ah + (RB + l15) * 256 + cbx);
    bf16x8 a0l = *(const bf16x8*)((const char*)Al + (RB + l15) * 256 + cbx);
    bf16x8 a1h = *(const bf16x8*)((const char*)Ah + (RB + 16 + l15) * 256 + cbx);
    bf16x8 a1l = *(const bf16x8*)((const char*)Al + (RB + 16 + l15) * 256 + cbx);
    #pragma unroll
    for (int n = 0; n < NFRAG; ++n) {
      const int wr = CB + n * 16 + l15;
      bf16x8 bh = *(const bf16x8*)((const char*)Wsh + wr * 256 + cbx);
      bf16x8 bl = *(const bf16x8*)((const char*)Wsl + wr * 256 + cbx);
      acc[0][n] = __builtin_amdgcn_mfma_f32_16x16x32_bf16(a0h, bh, acc[0][n], 0, 0, 0);
      acc[0][n] = __builtin_amdgcn_mfma_f32_16x16x32_bf16(a0h, bl, acc[0][n], 0, 0, 0);
      acc[0][n] = __builtin_amdgcn_mfma_f32_16x16x32_bf16(a0l, bh, acc[0][n], 0, 0, 0);
      acc[1][n] = __builtin_amdgcn_mfma_f32_16x16x32_bf16(a1h, bh, acc[1][n], 0, 0, 0);
      acc[1][n] = __builtin_amdgcn_mfma_f32_16x16x32_bf16(a1h, bl, acc[1][n], 0, 0, 0);
      acc[1][n] = __builtin_amdgcn_mfma_f32_16x16x32_bf16(a1l, bh, acc[1][n], 0, 0, 0);
    }
  }

  #pragma unroll
  for (int m = 0; m < 2; ++m) {
    #pragma unroll
    for (int q = 0; q < 4; ++q) {
      int row = rb + RB + m * 16 + l4 * 4 + q;
      if (row < N) {
        float dv = dinv[row];
        float* yr = Y + (size_t)row * COUT + CB + l15;
        #pragma unroll
        for (int n = 0; n < NFRAG; ++n) {
          float val = acc[m][n][q] * dv;
          yr[n * 16] = val;
          if (Y16) Y16[(size_t)row * COUT + CB + l15 + n * 16] = __float2half(val);
        }
      }
    }
  }
}

// ---------- vector GEMM (fallback path only) ----------
template<int COUT>
__launch_bounds__(256)
__global__ void k_gemm128(const float* __restrict__ X, const float* __restrict__ W,
                          const float* __restrict__ dinv, float* __restrict__ Y, int N) {
  constexpr int K = 128;
  constexpr int CG = COUT / 8;
  constexpr int ROWS = 256 / CG;
  constexpr int XSTR = K + 4;
  __shared__ float Ws[K * COUT];
  __shared__ float Xs[ROWS * XSTR];
  const int tid = threadIdx.x;

  const float4* W4 = (const float4*)W;
  float4* Ws4 = (float4*)Ws;
  #pragma unroll
  for (int i = tid; i < K * COUT / 4; i += 256) Ws4[i] = W4[i];

  const int rb = blockIdx.x * ROWS;
  float4* Xs4 = (float4*)Xs;
  for (int i = tid; i < ROWS * (K / 4); i += 256) {
    int r = i / (K / 4), c = i % (K / 4);
    float4 v = make_float4(0.f, 0.f, 0.f, 0.f);
    if (rb + r < N) v = ((const float4*)(X + (size_t)(rb + r) * K))[c];
    Xs4[r * (XSTR / 4) + c] = v;
  }
  __syncthreads();

  const int lrow = tid / CG;
  const int cg = tid % CG;
  const int row = rb + lrow;
  float acc[8];
  #pragma unroll
  for (int j = 0; j < 8; ++j) acc[j] = 0.f;
  const float* xr = Xs + lrow * XSTR;
  #pragma unroll 4
  for (int k = 0; k < K; ++k) {
    float xv = xr[k];
    float4 w0 = Ws4[k * (COUT / 4) + cg * 2];
    float4 w1 = Ws4[k * (COUT / 4) + cg * 2 + 1];
    acc[0] = fmaf(xv, w0.x, acc[0]);
    acc[1] = fmaf(xv, w0.y, acc[1]);
    acc[2] = fmaf(xv, w0.z, acc[2]);
    acc[3] = fmaf(xv, w0.w, acc[3]);
    acc[4] = fmaf(xv, w1.x, acc[4]);
    acc[5] = fmaf(xv, w1.y, acc[5]);
    acc[6] = fmaf(xv, w1.z, acc[6]);
    acc[7] = fmaf(xv, w1.w, acc[7]);
  }
  if (row < N) {
    float ds = dinv[row];
    float4* y = (float4*)(Y + (size_t)row * COUT + cg * 8);
    y[0] = make_float4(acc[0] * ds, acc[1] * ds, acc[2] * ds, acc[3] * ds);
    y[1] = make_float4(acc[4] * ds, acc[5] * ds, acc[6] * ds, acc[7] * ds);
  }
}

// ---------- vectorized CSR gather-aggregate: one WAVE per node, 2-deep pipeline ----------
// Lanes = (C/8 row-slices) x (NG neighbor groups); 16B gather per lane.
// Unroll x2: both col index loads issue together, then both gathers -> 2x MLP
// against the col->gather dependent-latency chain.
template<int C>
__launch_bounds__(256)
__global__ void k_aggv(const float* __restrict__ hsf, const __half* __restrict__ hsh,
                       const float* __restrict__ dinv, const int* __restrict__ rowptr,
                       const int* __restrict__ col, const float* __restrict__ bias,
                       float* __restrict__ out, int N) {
  constexpr int LPR = C / 8;           // lanes per row: 16 (C=128) / 8 (C=64)
  constexpr int NG = 64 / LPR;         // neighbors per gather instruction
  const int node = blockIdx.x * 4 + (threadIdx.x >> 6);
  if (node >= N) return;
  const int lane = threadIdx.x & 63;
  const int i = lane % LPR;
  const int j = lane / LPR;
  const int beg = rowptr[node], end = rowptr[node + 1];
  const size_t coloff = (size_t)i * 8;

  float acc[8];
  #pragma unroll
  for (int q = 0; q < 8; ++q) acc[q] = 0.f;

  for (int k = beg; k < end; k += 2 * NG) {
    int s0 = k + j, s1 = k + NG + j;
    bool ok0 = s0 < end, ok1 = s1 < end;
    int n0 = col[ok0 ? s0 : end - 1];
    int n1 = col[ok1 ? s1 : end - 1];
    uint4 v0 = *(const uint4*)((const char*)hsh + ((size_t)n0 * C + coloff) * 2);
    uint4 v1 = *(const uint4*)((const char*)hsh + ((size_t)n1 * C + coloff) * 2);
    float f0 = ok0 ? 1.f : 0.f;
    float f1 = ok1 ? 1.f : 0.f;
    const __half2* h0 = (const __half2*)&v0;
    const __half2* h1 = (const __half2*)&v1;
    #pragma unroll
    for (int q = 0; q < 4; ++q) {
      float2 a = __half22float2(h0[q]);
      float2 b = __half22float2(h1[q]);
      acc[2 * q]     = fmaf(f0, a.x, acc[2 * q]);
      acc[2 * q + 1] = fmaf(f0, a.y, acc[2 * q + 1]);
      acc[2 * q]     = fmaf(f1, b.x, acc[2 * q]);
      acc[2 * q + 1] = fmaf(f1, b.y, acc[2 * q + 1]);
    }
  }

  #pragma unroll
  for (int off = LPR; off < 64; off <<= 1)
    #pragma unroll
    for (int q = 0; q < 8; ++q)
      acc[q] += __shfl_xor(acc[q], off);

  if (j < 2) {
    const float dv = dinv[node];
    const int f4 = 2 * i + j;
    float4 sv = ((const float4*)(hsf + (size_t)node * C))[f4];
    float4 bb = ((const float4*)bias)[f4];
    float r0 = acc[4 * j + 0], r1 = acc[4 * j + 1];
    float r2 = acc[4 * j + 2], r3 = acc[4 * j + 3];
    float4 o;
    o.x = fmaxf(fmaf(dv, sv.x + r0, bb.x), 0.f);
    o.y = fmaxf(fmaf(dv, sv.y + r1, bb.y), 0.f);
    o.z = fmaxf(fmaf(dv, sv.z + r2, bb.z), 0.f);
    o.w = fmaxf(fmaf(dv, sv.w + r3, bb.w), 0.f);
    ((float4*)(out + (size_t)node * C))[f4] = o;
  }
}

// scalar fallback agg (no-fp16 path)
template<int C>
__launch_bounds__(C)
__global__ void k_agg(const float* __restrict__ hsf, const float* __restrict__ dinv,
                      const int* __restrict__ rowptr, const int* __restrict__ col,
                      const float* __restrict__ bias, float* __restrict__ out, int N) {
  const int node = blockIdx.x;
  const int tid = threadIdx.x;
  float acc = hsf[(size_t)node * C + tid];
  const int beg = rowptr[node];
  const int end = rowptr[node + 1];
  __shared__ int nb[C];
  for (int base = beg; base < end; base += C) {
    int m = min(C, end - base);
    if (tid < m) nb[tid] = col[base + tid];
    __syncthreads();
    for (int k = 0; k < m; ++k) acc += hsf[(size_t)nb[k] * C + tid];
    __syncthreads();
  }
  out[(size_t)node * C + tid] = fmaxf(fmaf(dinv[node], acc, bias[tid]), 0.f);
}

// ---------- fallback (atomic scatter) kernels ----------
__global__ void k_fill1(float* __restrict__ p, int n) {
  int i = blockIdx.x * blockDim.x + threadIdx.x;
  if (i < n) p[i] = 1.0f;
}
__global__ void k_deg_scatter(const int* __restrict__ dst, float* __restrict__ deg, int E) {
  int e = blockIdx.x * blockDim.x + threadIdx.x;
  if (e < E) atomicAdd(deg + dst[e], 1.0f);
}
__global__ void k_rsqrt_inplace(float* __restrict__ p, int n) {
  int i = blockIdx.x * blockDim.x + threadIdx.x;
  if (i < n) p[i] = rsqrtf(p[i]);
}
template<int C>
__global__ void k_selfinit2(const float* __restrict__ hs, const float* __restrict__ dinv,
                            float* __restrict__ agg, int N) {
  int i = blockIdx.x * blockDim.x + threadIdx.x;
  int total = N * (C / 4);
  if (i >= total) return;
  int node = i / (C / 4);
  float di = dinv[node];
  float4 v = ((const float4*)hs)[i];
  ((float4*)agg)[i] = make_float4(v.x * di, v.y * di, v.z * di, v.w * di);
}
template<int C>
__global__ void k_scatter(const float* __restrict__ hs, const float* __restrict__ dinv,
                          const int* __restrict__ src, const int* __restrict__ dst,
                          float* __restrict__ agg, int E) {
  constexpr int LPE = C / 4;
  long long t = (long long)blockIdx.x * blockDim.x + threadIdx.x;
  int e = (int)(t / LPE);
  if (e >= E) return;
  int c4 = (int)(t % LPE);
  int s = src[e], d = dst[e];
  float nd = dinv[d];
  float4 v = ((const float4*)(hs + (size_t)s * C))[c4];
  float* a = agg + (size_t)d * C + (size_t)c4 * 4;
  atomicAdd(a + 0, v.x * nd);
  atomicAdd(a + 1, v.y * nd);
  atomicAdd(a + 2, v.z * nd);
  atomicAdd(a + 3, v.w * nd);
}
template<int C>
__global__ void k_relu_bias(const float* __restrict__ agg, const float* __restrict__ b,
                            float* __restrict__ out, int N) {
  int i = blockIdx.x * blockDim.x + threadIdx.x;
  int total = N * (C / 4);
  if (i >= total) return;
  int c4 = i % (C / 4);
  float4 bb = ((const float4*)b)[c4];
  float4 v = ((const float4*)agg)[i];
  v.x = fmaxf(v.x + bb.x, 0.f);
  v.y = fmaxf(v.y + bb.y, 0.f);
  v.z = fmaxf(v.z + bb.z, 0.f);
  v.w = fmaxf(v.w + bb.w, 0.f);
  ((float4*)out)[i] = v;
}

extern "C" void kernel_launch(void* const* d_in, const int* in_sizes, int n_in,
                              void* d_out, int out_size, void* d_ws, size_t ws_size,
                              hipStream_t stream) {
  const float* x  = (const float*)d_in[0];
  const int*   ei = (const int*)d_in[1];
  const float* W1 = (const float*)d_in[2];
  const float* b1 = (const float*)d_in[3];
  const float* W2 = (const float*)d_in[4];
  const float* b2 = (const float*)d_in[5];

  const int Cin = 128, Chid = 128, Cout2 = 64;
  const int N = in_sizes[0] / Cin;
  const int E = in_sizes[1] / 2;
  const int* src = ei;
  const int* dst = ei + E;
  float* out = (float*)d_out;
  (void)n_in; (void)out_size;

  const int nbN = (N + TPB - 1) / TPB;
  const int nbE = (E + TPB - 1) / TPB;
  const int nbScan = (N + SCAN_B - 1) / SCAN_B;  // <= 1024 required

  auto align = [](size_t v) { return (v + 511) & ~(size_t)511; };
  char* ws = (char*)d_ws;
  size_t off = 0;
  float* dinv   = (float*)(ws + off); off += align((size_t)N * 4);
  int*   cnt    = (int*)(ws + off);   off += align((size_t)N * 4);   // reused as wpos
  int*   rowptr = (int*)(ws + off);   off += align((size_t)(N + 1) * 4);
  int*   bsum   = (int*)(ws + off);   off += align((size_t)nbScan * 4);
  unsigned short* wt1h = (unsigned short*)(ws + off); off += align((size_t)Cin * Chid * 2);
  unsigned short* wt1l = (unsigned short*)(ws + off); off += align((size_t)Cin * Chid * 2);
  unsigned short* wt2h = (unsigned short*)(ws + off); off += align((size_t)Chid * Cout2 * 2);
  unsigned short* wt2l = (unsigned short*)(ws + off); off += align((size_t)Chid * Cout2 * 2);
  int*   col    = (int*)(ws + off);   off += align((size_t)E * 4);
  float* A      = (float*)(ws + off); off += (size_t)N * Chid * 4;
  float* B      = (float*)(ws + off); off += (size_t)N * Chid * 4;
  const size_t off_csr = off;
  __half* H16   = (__half*)(ws + off); off += align((size_t)N * Chid * 2);
  const size_t off_fp16 = off;

  const bool csr_ok = (off_csr <= ws_size) && (nbScan <= 1024);
  const bool h16_ok = csr_ok && (off_fp16 <= ws_size);

  if (csr_ok) {
    // ---- degree + rowptr ----
    hipMemsetAsync(cnt, 0, (size_t)N * 4, stream);
    k_hist_xcd<<<2048, TPB, 0, stream>>>(dst, cnt, E, N);
    k_dinv_from_cnt<<<nbN, TPB, 0, stream>>>(cnt, dinv, N);
    k_scanA<<<nbScan, SCAN_B, 0, stream>>>(cnt, rowptr + 1, bsum, N);
    k_scanB<<<1, 1024, 0, stream>>>(bsum, nbScan);
    k_scanC<<<nbScan, SCAN_B, 0, stream>>>(rowptr, cnt, bsum, N);  // cnt becomes wpos

    // ---- CSR col fill (XCD-partitioned, write-amp-free) ----
    k_fillcsr_xcd<<<2048, TPB, 0, stream>>>(src, dst, cnt, col, E, N);

    // ---- W prep ----
    k_prep_wt<<<(Cin * Chid + TPB - 1) / TPB, TPB, 0, stream>>>(W1, wt1h, wt1l, Cin, Chid);
    k_prep_wt<<<(Chid * Cout2 + TPB - 1) / TPB, TPB, 0, stream>>>(W2, wt2h, wt2l, Chid, Cout2);

    __half* h16p = h16_ok ? H16 : (__half*)nullptr;

    // ---- layer 1: 128 -> 128 ----
    k_gemm_mfma<128><<<(N + 127) / 128, 512, 0, stream>>>(x, wt1h, wt1l, dinv, A, h16p, N);
    if (h16_ok) k_aggv<128><<<(N + 3) / 4, 256, 0, stream>>>(A, H16, dinv, rowptr, col, b1, B, N);
    else        k_agg<128><<<N, 128, 0, stream>>>(A, dinv, rowptr, col, b1, B, N);
    // ---- layer 2: 128 -> 64 ----
    k_gemm_mfma<64><<<(N + 127) / 128, 512, 0, stream>>>(B, wt2h, wt2l, dinv, A, h16p, N);
    if (h16_ok) k_aggv<64><<<(N + 3) / 4, 256, 0, stream>>>(A, H16, dinv, rowptr, col, b2, out, N);
    else        k_agg<64><<<N, 64, 0, stream>>>(A, dinv, rowptr, col, b2, out, N);
  } else {
    // ---- fallback: atomic-scatter path ----
    size_t o2 = 0;
    float* dinvF = (float*)(ws + o2); o2 += align((size_t)N * 4);
    float* AF = (float*)(ws + o2);    o2 += (size_t)N * Chid * 4;
    float* BF = (float*)(ws + o2);

    k_fill1<<<nbN, TPB, 0, stream>>>(dinvF, N);
    k_deg_scatter<<<nbE, TPB, 0, stream>>>(dst, dinvF, E);
    k_rsqrt_inplace<<<nbN, TPB, 0, stream>>>(dinvF, N);

    k_gemm128<128><<<(N + 15) / 16, 256, 0, stream>>>(x, W1, dinvF, AF, N);
    k_selfinit2<128><<<(N * 32 + TPB - 1) / TPB, TPB, 0, stream>>>(AF, dinvF, BF, N);
    {
      long long total = (long long)E * 32;
      k_scatter<128><<<(int)((total + TPB - 1) / TPB), TPB, 0, stream>>>(AF, dinvF, src, dst, BF, E);
    }
    k_relu_bias<128><<<(N * 32 + TPB - 1) / TPB, TPB, 0, stream>>>(BF, b1, AF, N);

    k_gemm128<64><<<(N + 31) / 32, 256, 0, stream>>>(AF, W2, dinvF, BF, N);
    k_selfinit2<64><<<(N * 16 + TPB - 1) / TPB, TPB, 0, stream>>>(BF, dinvF, out, N);
    {
      long long total = (long long)E * 16;
      k_scatter<64><<<(int)((total + TPB - 1) / TPB), TPB, 0, stream>>>(BF, dinvF, src, dst, out, E);
    }
    k_relu_bias<64><<<(N * 16 + TPB - 1) / TPB, TPB, 0, stream>>>(out, b2, out, N);
  }
}